// Round 24
// baseline (453.823 us; speedup 1.0000x reference)
//
#include <hip/hip_runtime.h>

// SNN forward: 3x (conv3x3 -> tdBN -> LIF -> maxpool2) + 2x (FC -> LIF)
// x [16,32,1,32,400] -> pool1 [16,32,6,16,200] -> pool2 [16,32,6,8,100]
//   -> pool3 [16,32,6,4,50] -> fc1 [16,32,100] -> out [16,32,2]
//
// Round-24: barrier halving in fuse1/fuse2. Double-buffer the input tile
// (small: +1.4KB / +6KB, under LDS occupancy caps) so staging merges into
// the conv phase (per-thread vmcnt wait replaces WG-wide drain). Per t:
// A{stage nxt, prefetch t+2, conv cur} -> bar -> B{partial} -> bar ->
// C{reduce} -> (no bar; next A's end-bar separates C's pr reads from next
// B's writes). 4 barriers/t -> 2 LDS-only. Arithmetic unchanged.

namespace {

constexpr int T = 16, B = 32;
constexpr int H1 = 32, W1 = 400, P1H = 16, P1W = 200;
constexpr int H2 = 16, W2 = 200, P2H = 8,  P2W = 100;
constexpr int H3 = 8,  W3 = 100, P3H = 4,  P3W = 50;

constexpr int NWG_S1 = T * B * (H1 / 32) * (W1 / 100);  // 2048
constexpr int NWG_F1 = B * (P1H / 4) * (P1W / 10);      // 2560
constexpr int NWG_F2 = B * (P2H / 4) * (P2W / 5);       // 1280

constexpr size_t OFF_PART1  = 0;
constexpr size_t OFF_PARTF1 = OFF_PART1 + (size_t)NWG_S1 * 12 * 8;
constexpr size_t OFF_PARTF2 = OFF_PARTF1 + (size_t)6400 * 12 * 8;  // slack
constexpr size_t OFF_STATS  = OFF_PARTF2 + (size_t)2560 * 12 * 8;
constexpr size_t OFF_POOL1  = 1310720;
constexpr size_t OFF_POOL2  = OFF_POOL1 + (size_t)T * B * 6 * P1H * P1W * 4;
constexpr size_t OFF_POOL3  = OFF_POOL2 + (size_t)T * B * 6 * P2H * P2W * 4;
constexpr size_t OFF_U1     = OFF_POOL3 + (size_t)T * B * 6 * P3H * P3W * 4;

} // namespace

// LDS-only phase barrier: waits own ds ops, does NOT drain vmcnt (prefetch
// loads stay in flight across it).
#define LDS_PHASE_BARRIER()                                   \
  do {                                                        \
    asm volatile("s_waitcnt lgkmcnt(0)" ::: "memory");        \
    __builtin_amdgcn_s_barrier();                             \
    __builtin_amdgcn_sched_barrier(0);                        \
  } while (0)

__device__ __forceinline__ float lif_step(float& v, float y) {
  v = v + (y - v) * 0.5f;                 // tau=2, decay_input
  float sp = (v >= 1.0f) ? 1.0f : 0.0f;   // threshold 1.0
  v = (sp > 0.0f) ? 0.0f : v;             // hard reset
  return sp;
}

// Block reduction of per-thread 6+6 double counters (array form).
__device__ __forceinline__ void reduce12(double* s, double* q, double* partials) {
  __shared__ double lds[4][12];
  int lane = threadIdx.x & 63, wid = threadIdx.x >> 6;
#pragma unroll
  for (int k = 0; k < 12; k++) {
    double v = (k < 6) ? s[k] : q[k - 6];
#pragma unroll
    for (int off = 32; off >= 1; off >>= 1) v += __shfl_down(v, off, 64);
    if (lane == 0) lds[wid][k] = v;
  }
  __syncthreads();
  if (threadIdx.x < 12) {
    partials[(size_t)blockIdx.x * 12 + threadIdx.x] =
        lds[0][threadIdx.x] + lds[1][threadIdx.x] + lds[2][threadIdx.x] + lds[3][threadIdx.x];
  }
}

// Select form: thread contributes (s_acc,q_acc) only to counter `oidx` (<0: none).
__device__ __forceinline__ void reduce12_sel(int oidx, double s_acc, double q_acc,
                                             double* partials) {
  __shared__ double lds[4][12];
  int lane = threadIdx.x & 63, wid = threadIdx.x >> 6;
#pragma unroll
  for (int k = 0; k < 12; k++) {
    double v = (k == oidx) ? s_acc : ((k == oidx + 6) ? q_acc : 0.0);
#pragma unroll
    for (int off = 32; off >= 1; off >>= 1) v += __shfl_down(v, off, 64);
    if (lane == 0) lds[wid][k] = v;
  }
  __syncthreads();
  if (threadIdx.x < 12) {
    partials[(size_t)blockIdx.x * 12 + threadIdx.x] =
        lds[0][threadIdx.x] + lds[1][threadIdx.x] + lds[2][threadIdx.x] + lds[3][threadIdx.x];
  }
}

// ---- block1 stats: conv(1->6) over x, LDS-tiled (single-shot) ----
template <int NC, int H, int W, int TH, int TW>
__global__ void conv_stats_lds(const float* __restrict__ in, const float* __restrict__ wt,
                               double* __restrict__ partials) {
  constexpr int IH = TH + 2, IW = TW + 2;
  constexpr int IWP = (IW & 1) ? IW : IW + 1;  // odd row stride
  constexpr int NW = NC * 54;
  constexpr int NTH = H / TH, NTW = W / TW;
  constexpr int NT = NTH * NTW;
  __shared__ float wsm[NW];
  __shared__ float tile[NC][IH][IWP];

  int tid = threadIdx.x;
  for (int k = tid; k < NW; k += blockDim.x) wsm[k] = wt[k];

  int wg = blockIdx.x;
  int tb = wg / NT;
  int ti = wg % NT;
  int ty = ti / NTW, tx = ti % NTW;
  int h0 = ty * TH - 1, w0 = tx * TW - 1;
  const float* xb = in + (size_t)tb * NC * H * W;

  for (int k = tid; k < NC * IH * IW; k += blockDim.x) {
    int i = k / (IH * IW);
    int r = k % (IH * IW);
    int rr = r / IW, cc = r % IW;
    int hh = h0 + rr, ww = w0 + cc;
    tile[i][rr][cc] = (hh >= 0 && hh < H && ww >= 0 && ww < W) ? xb[i * H * W + hh * W + ww] : 0.0f;
  }
  __syncthreads();

  double s[6] = {0, 0, 0, 0, 0, 0}, q[6] = {0, 0, 0, 0, 0, 0};
  for (int pos = tid; pos < TH * TW; pos += blockDim.x) {
    int ly = pos / TW, lx = pos % TW;
    float acc[6] = {0, 0, 0, 0, 0, 0};
#pragma unroll
    for (int i = 0; i < NC; i++) {
      float p[9];
#pragma unroll
      for (int ky = 0; ky < 3; ky++)
#pragma unroll
        for (int kx = 0; kx < 3; kx++) p[ky * 3 + kx] = tile[i][ly + ky][lx + kx];
#pragma unroll
      for (int o = 0; o < 6; o++) {
        float a = acc[o];
#pragma unroll
        for (int k2 = 0; k2 < 9; k2++) a = fmaf(p[k2], wsm[(o * NC + i) * 9 + k2], a);
        acc[o] = a;
      }
    }
#pragma unroll
    for (int o = 0; o < 6; o++) {
      s[o] += (double)acc[o];
      q[o] += (double)acc[o] * (double)acc[o];
    }
  }
  reduce12(s, q, partials);
}

// ---- finalize: partials -> mean[6], sg[6] ----
__global__ void finalize_stats(const double* __restrict__ partials, int nb, double n,
                               const float* __restrict__ gamma,
                               float* __restrict__ mean_out, float* __restrict__ sg_out) {
  __shared__ double lds[12][21];
  __shared__ double sums[12];
  int t = threadIdx.x;
  int k = t % 12, j = t / 12;
  if (t < 252) {
    double acc = 0.0;
    for (int b = j; b < nb; b += 21) acc += partials[(size_t)b * 12 + k];
    lds[k][j] = acc;
  }
  __syncthreads();
  if (t < 12) {
    double acc = 0.0;
#pragma unroll
    for (int j2 = 0; j2 < 21; j2++) acc += lds[t][j2];
    sums[t] = acc;
  }
  __syncthreads();
  if (t < 6) {
    double mean = sums[t] / n;
    double var = sums[t + 6] / n - mean * mean;
    double invstd = 1.0 / sqrt(var + 1e-5);
    mean_out[t] = (float)mean;
    sg_out[t] = (float)(invstd * (double)gamma[t]);
  }
}

// ---- fuse1 + stats2: own 4x10 pooled, halo 6x12, double-buffered tile ----
// til[buf][par][14][13]; WG: (b, oy 0..3, ox 0..19). 2 LDS barriers per t.
__global__ void fuse1_stats(const float* __restrict__ x, const float* __restrict__ w1g,
                            const float* __restrict__ w2g,
                            const float* __restrict__ mean1, const float* __restrict__ sg1,
                            const float* __restrict__ beta1,
                            float* __restrict__ pool1, double* __restrict__ partials2) {
  __shared__ float wsm2[324];
  __shared__ float til[2][2][14][13];  // [buf][par][row][col2]
  __shared__ float phl[432];           // ch*72 + hy*12 + hx
  __shared__ float pr[40][7][7];       // [pos][i][o]

  int tid = threadIdx.x;
  for (int k = tid; k < 324; k += 256) wsm2[k] = w2g[k];

  int wg = blockIdx.x;
  int b = wg / 80;
  int rem = wg % 80;
  int oy = rem / 20, ox = rem % 20;
  int iy0 = 8 * oy - 3, ix0 = 20 * ox - 3;  // input tile origin (14x26)

  // staging geometry (t-invariant): 364 raw elems, 2 slots/thread
  bool s_in[2];
  int s_off[2], s_lofs[2];
#pragma unroll
  for (int j = 0; j < 2; j++) {
    int k = tid + 256 * j;
    bool valid = k < 364;
    int srr = k / 26, scc = k % 26;
    int shh = iy0 + srr, sww = ix0 + scc;
    s_in[j] = valid && shh >= 0 && shh < H1 && sww >= 0 && sww < W1;
    s_off[j] = shh * W1 + sww;
    s_lofs[j] = valid ? ((scc & 1) * 182 + srr * 13 + (scc >> 1)) : -1;  // within-buffer
  }
  float* tilf = &til[0][0][0][0];

  // halo-conv geometry: 2 slots, pos = tid + 256*sl < 432
  int hch[2], hhy[2], hhx[2], hpy[2], hpx[2];
  bool hact[2], hval[2], hown[2];
  float m_[2], sc_[2], be_[2];
  float wv[2][9];
#pragma unroll
  for (int sl = 0; sl < 2; sl++) {
    int pos = tid + 256 * sl;
    hact[sl] = pos < 432;
    int p2 = hact[sl] ? pos : 0;
    int ch = p2 / 72;
    int r = p2 % 72;
    int hy = r / 12, hx = r % 12;
    hch[sl] = ch; hhy[sl] = hy; hhx[sl] = hx;
    int py = 4 * oy - 1 + hy, px = 10 * ox - 1 + hx;
    hpy[sl] = py; hpx[sl] = px;
    hval[sl] = hact[sl] && py >= 0 && py < P1H && px >= 0 && px < P1W;
    hown[sl] = hact[sl] && hy >= 1 && hy <= 4 && hx >= 1 && hx <= 10;
#pragma unroll
    for (int k = 0; k < 9; k++) wv[sl][k] = w1g[ch * 9 + k];
    m_[sl] = mean1[ch]; sc_[sl] = sg1[ch]; be_[sl] = beta1[ch];
  }

  // stats phases: 240 threads. partial: in-ch tid/40, pos40 = tid%40.
  int oidx = (tid < 240) ? (tid / 40) : -1;
  int pos40 = tid % 40;
  int psy = pos40 / 10, psx = pos40 % 10;

  float v[2][4];
#pragma unroll
  for (int sl = 0; sl < 2; sl++)
#pragma unroll
    for (int k = 0; k < 4; k++) v[sl][k] = 0.0f;
  double s_acc = 0.0, q_acc = 0.0;

  // prologue: load t=0, write buf0, prefetch t=1
  float rs[2] = {0.0f, 0.0f};
#pragma unroll
  for (int j = 0; j < 2; j++)
    if (s_in[j]) rs[j] = x[(size_t)(0 * B + b) * (H1 * W1) + s_off[j]];
#pragma unroll
  for (int j = 0; j < 2; j++)
    if (s_lofs[j] >= 0) tilf[s_lofs[j]] = rs[j];  // buf 0
#pragma unroll
  for (int j = 0; j < 2; j++)
    if (s_in[j]) rs[j] = x[(size_t)(1 * B + b) * (H1 * W1) + s_off[j]];
  LDS_PHASE_BARRIER();  // til[0] + wsm2 visible

  for (int t = 0; t < T; t++) {
    int cur = t & 1, nxt = cur ^ 1;
    // Phase A: stage til[nxt] (t+1), prefetch t+2, conv from til[cur]
    if (t + 1 < T) {
#pragma unroll
      for (int j = 0; j < 2; j++)
        if (s_lofs[j] >= 0) tilf[nxt * 364 + s_lofs[j]] = rs[j];  // per-thread vmcnt wait
    }
    if (t + 2 < T) {
#pragma unroll
      for (int j = 0; j < 2; j++)
        if (s_in[j]) rs[j] = x[(size_t)((t + 2) * B + b) * (H1 * W1) + s_off[j]];
    }
#pragma unroll
    for (int sl = 0; sl < 2; sl++) {
      if (hact[sl]) {
        float smax = 0.0f;
        if (hval[sl]) {
          int ry = 2 * hhy[sl], hx = hhx[sl];
          float p[16];
#pragma unroll
          for (int r = 0; r < 4; r++) {
            p[r * 4 + 0] = til[cur][0][ry + r][hx];
            p[r * 4 + 1] = til[cur][1][ry + r][hx];
            p[r * 4 + 2] = til[cur][0][ry + r][hx + 1];
            p[r * 4 + 3] = til[cur][1][ry + r][hx + 1];
          }
#pragma unroll
          for (int dy = 0; dy < 2; dy++) {
#pragma unroll
            for (int dx = 0; dx < 2; dx++) {
              float acc = 0.0f;
#pragma unroll
              for (int ky = 0; ky < 3; ky++)
#pragma unroll
                for (int kx = 0; kx < 3; kx++)
                  acc = fmaf(p[(dy + ky) * 4 + dx + kx], wv[sl][ky * 3 + kx], acc);
              float y = (acc - m_[sl]) * sc_[sl] + be_[sl];
              float sp = lif_step(v[sl][dy * 2 + dx], y);
              smax = fmaxf(smax, sp);
            }
          }
        }
        phl[tid + 256 * sl] = smax;  // == ch*72 + hy*12 + hx
        if (hown[sl])
          pool1[((size_t)(t * B + b) * 6 + hch[sl]) * (P1H * P1W) + hpy[sl] * P1W + hpx[sl]] = smax;
      }
    }
    LDS_PHASE_BARRIER();  // phl + til[nxt] writes done
    // Phase B: partial (reads phl, writes pr)
    if (oidx >= 0) {
      int i2 = oidx;
      float pt[9];
#pragma unroll
      for (int ky = 0; ky < 3; ky++)
#pragma unroll
        for (int kx = 0; kx < 3; kx++)
          pt[ky * 3 + kx] = phl[i2 * 72 + (psy + ky) * 12 + (psx + kx)];
      float p6[6];
#pragma unroll
      for (int o = 0; o < 6; o++) {
        float a = 0.0f;
#pragma unroll
        for (int k2 = 0; k2 < 9; k2++) a = fmaf(pt[k2], wsm2[(o * 6 + i2) * 9 + k2], a);
        p6[o] = a;
      }
#pragma unroll
      for (int o = 0; o < 6; o++) pr[pos40][i2][o] = p6[o];
    }
    LDS_PHASE_BARRIER();  // pr ready
    // Phase C: reduce (reads pr). No barrier: next A's end-barrier separates
    // these reads from the next B's pr writes; A touches only til/phl.
    if (oidx >= 0) {
      double acc = 0.0;
#pragma unroll
      for (int ic = 0; ic < 6; ic++) acc += (double)pr[pos40][ic][oidx];
      s_acc += acc;
      q_acc += acc * acc;
    }
  }
  __syncthreads();
  reduce12_sel(oidx, s_acc, q_acc, partials2);
}

// ---- fuse2 + stats3: own 4x5 pooled, halo 6x7, double-buffered tile ----
// til[buf][par][6][14][9]; 2 LDS barriers per t.
__global__ void fuse2_stats(const float* __restrict__ in, const float* __restrict__ w2g,
                            const float* __restrict__ w3g,
                            const float* __restrict__ mean2, const float* __restrict__ sg2,
                            const float* __restrict__ beta2,
                            float* __restrict__ pool2, double* __restrict__ partials3) {
  __shared__ float wsm2[324];
  __shared__ float wsm3[324];
  __shared__ float til[2][2][6][14][9];  // [buf][par][ch][row][col2]
  __shared__ float phl[6][6][7];
  __shared__ float pr[20][6][7];         // [pos][i][o]

  int tid = threadIdx.x;
  for (int k = tid; k < 324; k += 256) { wsm2[k] = w2g[k]; wsm3[k] = w3g[k]; }

  int wg = blockIdx.x;
  int b = wg / 40;
  int rem = wg % 40;
  int oy = rem / 20, ox = rem % 20;
  int iy0 = 8 * oy - 3, ix0 = 10 * ox - 3;
  constexpr int HW = H2 * W2;

  bool s_in[6];
  int s_off[6], s_lofs[6];
#pragma unroll
  for (int j = 0; j < 6; j++) {
    int k = tid + 256 * j;
    bool valid = k < 1344;
    int i = k / 224;
    int r2 = k % 224;
    int rr = r2 / 16, cc = r2 % 16;
    int hh = iy0 + rr, ww = ix0 + cc;
    s_in[j] = valid && hh >= 0 && hh < H2 && ww >= 0 && ww < W2;
    s_off[j] = i * HW + hh * W2 + ww;
    s_lofs[j] = valid ? ((cc & 1) * 756 + i * 126 + rr * 9 + (cc >> 1)) : -1;  // within-buffer
  }
  float* tilf = &til[0][0][0][0][0];

  bool active = tid < 252;
  int ch = 0, hy = 0, hx = 0, py = 0, px = 0;
  bool pvalid = false, own = false;
  if (active) {
    ch = tid / 42;
    int r = tid % 42;
    hy = r / 7; hx = r % 7;
    py = 4 * oy - 1 + hy; px = 5 * ox - 1 + hx;
    pvalid = (py >= 0 && py < P2H && px >= 0 && px < P2W);
    own = (hy >= 1 && hy <= 4 && hx >= 1 && hx <= 5);
  }
  float m = active ? mean2[ch] : 0.0f;
  float sc = active ? sg2[ch] : 0.0f;
  float be = active ? beta2[ch] : 0.0f;

  int oidx = (tid < 120) ? (tid / 20) : -1;
  int pos = tid % 20;
  int psy = pos / 5, psx = pos % 5;

  float v[4] = {0.0f, 0.0f, 0.0f, 0.0f};
  double s_acc = 0.0, q_acc = 0.0;

  // prologue: load t=0, write buf0, prefetch t=1
  float rs[6] = {0.0f, 0.0f, 0.0f, 0.0f, 0.0f, 0.0f};
  {
    const float* xb = in + (size_t)(0 * B + b) * 6 * HW;
#pragma unroll
    for (int j = 0; j < 6; j++)
      if (s_in[j]) rs[j] = xb[s_off[j]];
  }
#pragma unroll
  for (int j = 0; j < 6; j++)
    if (s_lofs[j] >= 0) tilf[s_lofs[j]] = rs[j];  // buf 0
  {
    const float* xb = in + (size_t)(1 * B + b) * 6 * HW;
#pragma unroll
    for (int j = 0; j < 6; j++)
      if (s_in[j]) rs[j] = xb[s_off[j]];
  }
  LDS_PHASE_BARRIER();  // til[0] + weights visible

  for (int t = 0; t < T; t++) {
    int cur = t & 1, nxt = cur ^ 1;
    // Phase A: stage til[nxt] (t+1), prefetch t+2, conv from til[cur]
    if (t + 1 < T) {
#pragma unroll
      for (int j = 0; j < 6; j++)
        if (s_lofs[j] >= 0) tilf[nxt * 1512 + s_lofs[j]] = rs[j];
    }
    if (t + 2 < T) {
      const float* xb = in + (size_t)((t + 2) * B + b) * 6 * HW;
#pragma unroll
      for (int j = 0; j < 6; j++)
        if (s_in[j]) rs[j] = xb[s_off[j]];
    }
    if (active) {
      float smax = 0.0f;
      if (pvalid) {
        int ry = 2 * hy;
        float acc4[4] = {0.0f, 0.0f, 0.0f, 0.0f};
#pragma unroll
        for (int i = 0; i < 6; i++) {
          float p[16];
#pragma unroll
          for (int r = 0; r < 4; r++) {
            p[r * 4 + 0] = til[cur][0][i][ry + r][hx];
            p[r * 4 + 1] = til[cur][1][i][ry + r][hx];
            p[r * 4 + 2] = til[cur][0][i][ry + r][hx + 1];
            p[r * 4 + 3] = til[cur][1][i][ry + r][hx + 1];
          }
          const float* wo = &wsm2[(ch * 6 + i) * 9];
#pragma unroll
          for (int dy = 0; dy < 2; dy++)
#pragma unroll
            for (int dx = 0; dx < 2; dx++) {
              float a = acc4[dy * 2 + dx];
#pragma unroll
              for (int ky = 0; ky < 3; ky++)
#pragma unroll
                for (int kx = 0; kx < 3; kx++)
                  a = fmaf(p[(dy + ky) * 4 + dx + kx], wo[ky * 3 + kx], a);
              acc4[dy * 2 + dx] = a;
            }
        }
#pragma unroll
        for (int p4 = 0; p4 < 4; p4++) {
          float y = (acc4[p4] - m) * sc + be;
          float sp = lif_step(v[p4], y);
          smax = fmaxf(smax, sp);
        }
      }
      phl[ch][hy][hx] = smax;
      if (own)
        pool2[((size_t)(t * B + b) * 6 + ch) * (P2H * P2W) + py * P2W + px] = smax;
    }
    LDS_PHASE_BARRIER();  // phl + til[nxt] done
    // Phase B: partial
    if (oidx >= 0) {
      float pt[9];
#pragma unroll
      for (int ky = 0; ky < 3; ky++)
#pragma unroll
        for (int kx = 0; kx < 3; kx++)
          pt[ky * 3 + kx] = phl[oidx][psy + ky][psx + kx];
      float p6[6];
#pragma unroll
      for (int o = 0; o < 6; o++) {
        float a = 0.0f;
#pragma unroll
        for (int k2 = 0; k2 < 9; k2++) a = fmaf(pt[k2], wsm3[(o * 6 + oidx) * 9 + k2], a);
        p6[o] = a;
      }
#pragma unroll
      for (int o = 0; o < 6; o++) pr[pos][oidx][o] = p6[o];
    }
    LDS_PHASE_BARRIER();  // pr ready
    // Phase C: reduce (no barrier; next A's end-barrier separates)
    if (oidx >= 0) {
      double acc = 0.0;
#pragma unroll
      for (int ic = 0; ic < 6; ic++) acc += (double)pr[pos][ic][oidx];
      s_acc += acc;
      q_acc += acc * acc;
    }
  }
  __syncthreads();
  reduce12_sel(oidx, s_acc, q_acc, partials3);
}

// ---- block 3 fuse: conv(6->6)+BN+LIF+pool, parity-split LDS tiles ----
template <int H, int W, int PH, int PW, int TH, int TW>
__global__ void block6_fuse_lds(const float* __restrict__ in, const float* __restrict__ wt,
                                const float* __restrict__ mean, const float* __restrict__ sg,
                                const float* __restrict__ beta, float* __restrict__ out) {
  constexpr int NTH = PH / TH, NTW = PW / TW;
  constexpr int IH = 2 * TH + 2, IW = 2 * TW + 2;
  constexpr int EW = IW / 2;
  constexpr int TILE_N = IH * IW;
  constexpr int NACT = 6 * TH * TW;
  constexpr int HW = H * W;
  __shared__ float wsm[324];
  __shared__ float til_e[6][IH][EW];
  __shared__ float til_o[6][IH][EW];

  for (int k = threadIdx.x; k < 324; k += blockDim.x) wsm[k] = wt[k];

  int wg = blockIdx.x;
  int b = wg / (NTH * NTW);
  int tid2 = wg % (NTH * NTW);
  int ty = tid2 / NTW, tx = tid2 % NTW;
  int h_in0 = 2 * (ty * TH) - 1, w_in0 = 2 * (tx * TW) - 1;

  int tid = threadIdx.x;
  int o = 0, lph = 0, lpw = 0;
  if (tid < NACT) {
    o = tid / (TH * TW);
    int r = tid % (TH * TW);
    lph = r / TW; lpw = r % TW;
  }
  float m = mean[o], s = sg[o], be = beta[o];
  float v[4] = {0.0f, 0.0f, 0.0f, 0.0f};

  for (int t = 0; t < T; t++) {
    __syncthreads();
    const float* xb = in + (size_t)(t * B + b) * 6 * HW;
    for (int k = tid; k < 6 * TILE_N; k += blockDim.x) {
      int i = k / TILE_N;
      int r2 = k % TILE_N;
      int rr = r2 / IW, cc = r2 % IW;
      int hh = h_in0 + rr, ww = w_in0 + cc;
      float val = (hh >= 0 && hh < H && ww >= 0 && ww < W) ? xb[i * HW + hh * W + ww] : 0.0f;
      if (cc & 1) til_o[i][rr][cc >> 1] = val;
      else        til_e[i][rr][cc >> 1] = val;
    }
    __syncthreads();
    if (tid < NACT) {
      int ry = 2 * lph;
      float acc[4] = {0.0f, 0.0f, 0.0f, 0.0f};
#pragma unroll
      for (int i = 0; i < 6; i++) {
        float p[16];
#pragma unroll
        for (int r = 0; r < 4; r++) {
          p[r * 4 + 0] = til_e[i][ry + r][lpw];
          p[r * 4 + 1] = til_o[i][ry + r][lpw];
          p[r * 4 + 2] = til_e[i][ry + r][lpw + 1];
          p[r * 4 + 3] = til_o[i][ry + r][lpw + 1];
        }
        const float* wo = &wsm[(o * 6 + i) * 9];
#pragma unroll
        for (int dy = 0; dy < 2; dy++)
#pragma unroll
          for (int dx = 0; dx < 2; dx++) {
            float a = acc[dy * 2 + dx];
#pragma unroll
            for (int ky = 0; ky < 3; ky++)
#pragma unroll
              for (int kx = 0; kx < 3; kx++)
                a = fmaf(p[(dy + ky) * 4 + dx + kx], wo[ky * 3 + kx], a);
            acc[dy * 2 + dx] = a;
          }
      }
      float smax = 0.0f;
#pragma unroll
      for (int p4 = 0; p4 < 4; p4++) {
        float y = (acc[p4] - m) * s + be;
        float sp = lif_step(v[p4], y);
        smax = fmaxf(smax, sp);
      }
      out[((size_t)(t * B + b) * 6 + o) * (PH * PW) + (ty * TH + lph) * PW + (tx * TW + lpw)] = smax;
    }
  }
}

// ---- FC1 matmul ----
__global__ void fc1_mm(const float* __restrict__ p3, const float* __restrict__ fw1,
                       float* __restrict__ u1) {
  int idx = blockIdx.x * blockDim.x + threadIdx.x;
  if (idx >= T * B * 100) return;
  int o = idx % 100;
  int tb = idx / 100;
  const float4* x4 = (const float4*)(p3 + (size_t)tb * 1200);
  const float4* w4 = (const float4*)(fw1 + (size_t)o * 1200);
  float acc = 0.0f;
#pragma unroll 4
  for (int k = 0; k < 300; k++) {
    float4 a = x4[k], w = w4[k];
    acc = fmaf(a.x, w.x, acc);
    acc = fmaf(a.y, w.y, acc);
    acc = fmaf(a.z, w.z, acc);
    acc = fmaf(a.w, w.w, acc);
  }
  u1[idx] = acc;
}

// ---- fc tail: fc1-LIF + fc2 + fc2-LIF, one WG per batch ----
__global__ void fc_tail(const float* __restrict__ u1, const float* __restrict__ fw2,
                        float* __restrict__ outp) {
  __shared__ float s1[100];
  __shared__ float w2s[200];
  int b = blockIdx.x;
  int tid = threadIdx.x;
  for (int k = tid; k < 200; k += 128) w2s[k] = fw2[k];
  float v1 = 0.0f, v2 = 0.0f;
  __syncthreads();
  for (int t = 0; t < T; t++) {
    if (tid < 100) {
      float sp = lif_step(v1, u1[(size_t)(t * B + b) * 100 + tid]);
      s1[tid] = sp;
    }
    __syncthreads();
    if (tid < 2) {
      const float* wr = &w2s[tid * 100];
      float acc = 0.0f;
#pragma unroll
      for (int k = 0; k < 100; k++) acc = fmaf(s1[k], wr[k], acc);
      float sp = lif_step(v2, acc);
      outp[(size_t)(t * B + b) * 2 + tid] = sp;
    }
    __syncthreads();
  }
}

extern "C" void kernel_launch(void* const* d_in, const int* in_sizes, int n_in,
                              void* d_out, int out_size, void* d_ws, size_t ws_size,
                              hipStream_t stream) {
  const float* x   = (const float*)d_in[0];
  const float* w1  = (const float*)d_in[1];
  const float* g1  = (const float*)d_in[2];
  const float* b1  = (const float*)d_in[3];
  const float* w2  = (const float*)d_in[4];
  const float* g2  = (const float*)d_in[5];
  const float* b2  = (const float*)d_in[6];
  const float* w3  = (const float*)d_in[7];
  const float* g3  = (const float*)d_in[8];
  const float* b3  = (const float*)d_in[9];
  const float* fw1 = (const float*)d_in[10];
  const float* fw2 = (const float*)d_in[11];
  float* out = (float*)d_out;

  char* ws = (char*)d_ws;
  double* part1  = (double*)(ws + OFF_PART1);
  double* partf1 = (double*)(ws + OFF_PARTF1);
  double* partf2 = (double*)(ws + OFF_PARTF2);
  float* mean1 = (float*)(ws + OFF_STATS + 0);
  float* sg1   = (float*)(ws + OFF_STATS + 32);
  float* mean2 = (float*)(ws + OFF_STATS + 64);
  float* sg2   = (float*)(ws + OFF_STATS + 96);
  float* mean3 = (float*)(ws + OFF_STATS + 128);
  float* sg3   = (float*)(ws + OFF_STATS + 160);
  float* pool1 = (float*)(ws + OFF_POOL1);
  float* pool2 = (float*)(ws + OFF_POOL2);
  float* pool3 = (float*)(ws + OFF_POOL3);
  float* u1    = (float*)(ws + OFF_U1);

  // Block 1 stats + finalize
  conv_stats_lds<1, H1, W1, 32, 100><<<NWG_S1, 256, 0, stream>>>(x, w1, part1);
  finalize_stats<<<1, 256, 0, stream>>>(part1, NWG_S1, (double)T * B * H1 * W1, g1, mean1, sg1);
  // fuse1 (+ stats for block2)
  fuse1_stats<<<NWG_F1, 256, 0, stream>>>(x, w1, w2, mean1, sg1, b1, pool1, partf1);
  finalize_stats<<<1, 256, 0, stream>>>(partf1, NWG_F1, (double)T * B * H2 * W2, g2, mean2, sg2);
  // fuse2 (+ stats for block3)
  fuse2_stats<<<NWG_F2, 256, 0, stream>>>(pool1, w2, w3, mean2, sg2, b2, pool2, partf2);
  finalize_stats<<<1, 256, 0, stream>>>(partf2, NWG_F2, (double)T * B * H3 * W3, g3, mean3, sg3);
  // Block 3 fuse
  {
    int nwg = B * (P3H / 2) * (P3W / 5);  // 640
    block6_fuse_lds<H3, W3, P3H, P3W, 2, 5><<<nwg, 64, 0, stream>>>(pool2, w3, mean3, sg3, b3, pool3);
  }
  // FC head
  {
    int n = T * B * 100;
    fc1_mm<<<(n + 255) / 256, 256, 0, stream>>>(pool3, fw1, u1);
  }
  fc_tail<<<B, 128, 0, stream>>>(u1, fw2, out);
}

// Round 25
// 438.019 us; speedup vs baseline: 1.0361x; 1.0361x over previous
//
#include <hip/hip_runtime.h>

// SNN forward: 3x (conv3x3 -> tdBN -> LIF -> maxpool2) + 2x (FC -> LIF)
// x [16,32,1,32,400] -> pool1 [16,32,6,16,200] -> pool2 [16,32,6,8,100]
//   -> pool3 [16,32,6,4,50] -> fc1 [16,32,100] -> out [16,32,2]
//
// Round-25: A/B hybrid. r24's dbuf+2-barrier FUSE1 kept (its +1.4KB stayed
// under the LDS occupancy cap; left the top-5). FUSE2 reverted to r20
// single-buffer (r24's dbuf pushed it 12.5->19.5KB, occ 56->33%, 132us).
// Total delta vs 433 isolates fuse1-dbuf's true contribution.

namespace {

constexpr int T = 16, B = 32;
constexpr int H1 = 32, W1 = 400, P1H = 16, P1W = 200;
constexpr int H2 = 16, W2 = 200, P2H = 8,  P2W = 100;
constexpr int H3 = 8,  W3 = 100, P3H = 4,  P3W = 50;

constexpr int NWG_S1 = T * B * (H1 / 32) * (W1 / 100);  // 2048
constexpr int NWG_F1 = B * (P1H / 4) * (P1W / 10);      // 2560
constexpr int NWG_F2 = B * (P2H / 4) * (P2W / 5);       // 1280

constexpr size_t OFF_PART1  = 0;
constexpr size_t OFF_PARTF1 = OFF_PART1 + (size_t)NWG_S1 * 12 * 8;
constexpr size_t OFF_PARTF2 = OFF_PARTF1 + (size_t)6400 * 12 * 8;  // slack
constexpr size_t OFF_STATS  = OFF_PARTF2 + (size_t)2560 * 12 * 8;
constexpr size_t OFF_POOL1  = 1310720;
constexpr size_t OFF_POOL2  = OFF_POOL1 + (size_t)T * B * 6 * P1H * P1W * 4;
constexpr size_t OFF_POOL3  = OFF_POOL2 + (size_t)T * B * 6 * P2H * P2W * 4;
constexpr size_t OFF_U1     = OFF_POOL3 + (size_t)T * B * 6 * P3H * P3W * 4;

} // namespace

// LDS-only phase barrier: waits own ds ops, does NOT drain vmcnt (prefetch
// loads stay in flight across it).
#define LDS_PHASE_BARRIER()                                   \
  do {                                                        \
    asm volatile("s_waitcnt lgkmcnt(0)" ::: "memory");        \
    __builtin_amdgcn_s_barrier();                             \
    __builtin_amdgcn_sched_barrier(0);                        \
  } while (0)

__device__ __forceinline__ float lif_step(float& v, float y) {
  v = v + (y - v) * 0.5f;                 // tau=2, decay_input
  float sp = (v >= 1.0f) ? 1.0f : 0.0f;   // threshold 1.0
  v = (sp > 0.0f) ? 0.0f : v;             // hard reset
  return sp;
}

// Block reduction of per-thread 6+6 double counters (array form).
__device__ __forceinline__ void reduce12(double* s, double* q, double* partials) {
  __shared__ double lds[4][12];
  int lane = threadIdx.x & 63, wid = threadIdx.x >> 6;
#pragma unroll
  for (int k = 0; k < 12; k++) {
    double v = (k < 6) ? s[k] : q[k - 6];
#pragma unroll
    for (int off = 32; off >= 1; off >>= 1) v += __shfl_down(v, off, 64);
    if (lane == 0) lds[wid][k] = v;
  }
  __syncthreads();
  if (threadIdx.x < 12) {
    partials[(size_t)blockIdx.x * 12 + threadIdx.x] =
        lds[0][threadIdx.x] + lds[1][threadIdx.x] + lds[2][threadIdx.x] + lds[3][threadIdx.x];
  }
}

// Select form: thread contributes (s_acc,q_acc) only to counter `oidx` (<0: none).
__device__ __forceinline__ void reduce12_sel(int oidx, double s_acc, double q_acc,
                                             double* partials) {
  __shared__ double lds[4][12];
  int lane = threadIdx.x & 63, wid = threadIdx.x >> 6;
#pragma unroll
  for (int k = 0; k < 12; k++) {
    double v = (k == oidx) ? s_acc : ((k == oidx + 6) ? q_acc : 0.0);
#pragma unroll
    for (int off = 32; off >= 1; off >>= 1) v += __shfl_down(v, off, 64);
    if (lane == 0) lds[wid][k] = v;
  }
  __syncthreads();
  if (threadIdx.x < 12) {
    partials[(size_t)blockIdx.x * 12 + threadIdx.x] =
        lds[0][threadIdx.x] + lds[1][threadIdx.x] + lds[2][threadIdx.x] + lds[3][threadIdx.x];
  }
}

// ---- block1 stats: conv(1->6) over x, LDS-tiled (single-shot) ----
template <int NC, int H, int W, int TH, int TW>
__global__ void conv_stats_lds(const float* __restrict__ in, const float* __restrict__ wt,
                               double* __restrict__ partials) {
  constexpr int IH = TH + 2, IW = TW + 2;
  constexpr int IWP = (IW & 1) ? IW : IW + 1;  // odd row stride
  constexpr int NW = NC * 54;
  constexpr int NTH = H / TH, NTW = W / TW;
  constexpr int NT = NTH * NTW;
  __shared__ float wsm[NW];
  __shared__ float tile[NC][IH][IWP];

  int tid = threadIdx.x;
  for (int k = tid; k < NW; k += blockDim.x) wsm[k] = wt[k];

  int wg = blockIdx.x;
  int tb = wg / NT;
  int ti = wg % NT;
  int ty = ti / NTW, tx = ti % NTW;
  int h0 = ty * TH - 1, w0 = tx * TW - 1;
  const float* xb = in + (size_t)tb * NC * H * W;

  for (int k = tid; k < NC * IH * IW; k += blockDim.x) {
    int i = k / (IH * IW);
    int r = k % (IH * IW);
    int rr = r / IW, cc = r % IW;
    int hh = h0 + rr, ww = w0 + cc;
    tile[i][rr][cc] = (hh >= 0 && hh < H && ww >= 0 && ww < W) ? xb[i * H * W + hh * W + ww] : 0.0f;
  }
  __syncthreads();

  double s[6] = {0, 0, 0, 0, 0, 0}, q[6] = {0, 0, 0, 0, 0, 0};
  for (int pos = tid; pos < TH * TW; pos += blockDim.x) {
    int ly = pos / TW, lx = pos % TW;
    float acc[6] = {0, 0, 0, 0, 0, 0};
#pragma unroll
    for (int i = 0; i < NC; i++) {
      float p[9];
#pragma unroll
      for (int ky = 0; ky < 3; ky++)
#pragma unroll
        for (int kx = 0; kx < 3; kx++) p[ky * 3 + kx] = tile[i][ly + ky][lx + kx];
#pragma unroll
      for (int o = 0; o < 6; o++) {
        float a = acc[o];
#pragma unroll
        for (int k2 = 0; k2 < 9; k2++) a = fmaf(p[k2], wsm[(o * NC + i) * 9 + k2], a);
        acc[o] = a;
      }
    }
#pragma unroll
    for (int o = 0; o < 6; o++) {
      s[o] += (double)acc[o];
      q[o] += (double)acc[o] * (double)acc[o];
    }
  }
  reduce12(s, q, partials);
}

// ---- finalize: partials -> mean[6], sg[6] ----
__global__ void finalize_stats(const double* __restrict__ partials, int nb, double n,
                               const float* __restrict__ gamma,
                               float* __restrict__ mean_out, float* __restrict__ sg_out) {
  __shared__ double lds[12][21];
  __shared__ double sums[12];
  int t = threadIdx.x;
  int k = t % 12, j = t / 12;
  if (t < 252) {
    double acc = 0.0;
    for (int b = j; b < nb; b += 21) acc += partials[(size_t)b * 12 + k];
    lds[k][j] = acc;
  }
  __syncthreads();
  if (t < 12) {
    double acc = 0.0;
#pragma unroll
    for (int j2 = 0; j2 < 21; j2++) acc += lds[t][j2];
    sums[t] = acc;
  }
  __syncthreads();
  if (t < 6) {
    double mean = sums[t] / n;
    double var = sums[t + 6] / n - mean * mean;
    double invstd = 1.0 / sqrt(var + 1e-5);
    mean_out[t] = (float)mean;
    sg_out[t] = (float)(invstd * (double)gamma[t]);
  }
}

// ---- fuse1 + stats2: own 4x10 pooled, halo 6x12, double-buffered tile ----
// til[buf][par][14][13]; WG: (b, oy 0..3, ox 0..19). 2 LDS barriers per t.
__global__ void fuse1_stats(const float* __restrict__ x, const float* __restrict__ w1g,
                            const float* __restrict__ w2g,
                            const float* __restrict__ mean1, const float* __restrict__ sg1,
                            const float* __restrict__ beta1,
                            float* __restrict__ pool1, double* __restrict__ partials2) {
  __shared__ float wsm2[324];
  __shared__ float til[2][2][14][13];  // [buf][par][row][col2]
  __shared__ float phl[432];           // ch*72 + hy*12 + hx
  __shared__ float pr[40][7][7];       // [pos][i][o]

  int tid = threadIdx.x;
  for (int k = tid; k < 324; k += 256) wsm2[k] = w2g[k];

  int wg = blockIdx.x;
  int b = wg / 80;
  int rem = wg % 80;
  int oy = rem / 20, ox = rem % 20;
  int iy0 = 8 * oy - 3, ix0 = 20 * ox - 3;  // input tile origin (14x26)

  // staging geometry (t-invariant): 364 raw elems, 2 slots/thread
  bool s_in[2];
  int s_off[2], s_lofs[2];
#pragma unroll
  for (int j = 0; j < 2; j++) {
    int k = tid + 256 * j;
    bool valid = k < 364;
    int srr = k / 26, scc = k % 26;
    int shh = iy0 + srr, sww = ix0 + scc;
    s_in[j] = valid && shh >= 0 && shh < H1 && sww >= 0 && sww < W1;
    s_off[j] = shh * W1 + sww;
    s_lofs[j] = valid ? ((scc & 1) * 182 + srr * 13 + (scc >> 1)) : -1;  // within-buffer
  }
  float* tilf = &til[0][0][0][0];

  // halo-conv geometry: 2 slots, pos = tid + 256*sl < 432
  int hch[2], hhy[2], hhx[2], hpy[2], hpx[2];
  bool hact[2], hval[2], hown[2];
  float m_[2], sc_[2], be_[2];
  float wv[2][9];
#pragma unroll
  for (int sl = 0; sl < 2; sl++) {
    int pos = tid + 256 * sl;
    hact[sl] = pos < 432;
    int p2 = hact[sl] ? pos : 0;
    int ch = p2 / 72;
    int r = p2 % 72;
    int hy = r / 12, hx = r % 12;
    hch[sl] = ch; hhy[sl] = hy; hhx[sl] = hx;
    int py = 4 * oy - 1 + hy, px = 10 * ox - 1 + hx;
    hpy[sl] = py; hpx[sl] = px;
    hval[sl] = hact[sl] && py >= 0 && py < P1H && px >= 0 && px < P1W;
    hown[sl] = hact[sl] && hy >= 1 && hy <= 4 && hx >= 1 && hx <= 10;
#pragma unroll
    for (int k = 0; k < 9; k++) wv[sl][k] = w1g[ch * 9 + k];
    m_[sl] = mean1[ch]; sc_[sl] = sg1[ch]; be_[sl] = beta1[ch];
  }

  // stats phases: 240 threads. partial: in-ch tid/40, pos40 = tid%40.
  int oidx = (tid < 240) ? (tid / 40) : -1;
  int pos40 = tid % 40;
  int psy = pos40 / 10, psx = pos40 % 10;

  float v[2][4];
#pragma unroll
  for (int sl = 0; sl < 2; sl++)
#pragma unroll
    for (int k = 0; k < 4; k++) v[sl][k] = 0.0f;
  double s_acc = 0.0, q_acc = 0.0;

  // prologue: load t=0, write buf0, prefetch t=1
  float rs[2] = {0.0f, 0.0f};
#pragma unroll
  for (int j = 0; j < 2; j++)
    if (s_in[j]) rs[j] = x[(size_t)(0 * B + b) * (H1 * W1) + s_off[j]];
#pragma unroll
  for (int j = 0; j < 2; j++)
    if (s_lofs[j] >= 0) tilf[s_lofs[j]] = rs[j];  // buf 0
#pragma unroll
  for (int j = 0; j < 2; j++)
    if (s_in[j]) rs[j] = x[(size_t)(1 * B + b) * (H1 * W1) + s_off[j]];
  LDS_PHASE_BARRIER();  // til[0] + wsm2 visible

  for (int t = 0; t < T; t++) {
    int cur = t & 1, nxt = cur ^ 1;
    // Phase A: stage til[nxt] (t+1), prefetch t+2, conv from til[cur]
    if (t + 1 < T) {
#pragma unroll
      for (int j = 0; j < 2; j++)
        if (s_lofs[j] >= 0) tilf[nxt * 364 + s_lofs[j]] = rs[j];  // per-thread vmcnt wait
    }
    if (t + 2 < T) {
#pragma unroll
      for (int j = 0; j < 2; j++)
        if (s_in[j]) rs[j] = x[(size_t)((t + 2) * B + b) * (H1 * W1) + s_off[j]];
    }
#pragma unroll
    for (int sl = 0; sl < 2; sl++) {
      if (hact[sl]) {
        float smax = 0.0f;
        if (hval[sl]) {
          int ry = 2 * hhy[sl], hx = hhx[sl];
          float p[16];
#pragma unroll
          for (int r = 0; r < 4; r++) {
            p[r * 4 + 0] = til[cur][0][ry + r][hx];
            p[r * 4 + 1] = til[cur][1][ry + r][hx];
            p[r * 4 + 2] = til[cur][0][ry + r][hx + 1];
            p[r * 4 + 3] = til[cur][1][ry + r][hx + 1];
          }
#pragma unroll
          for (int dy = 0; dy < 2; dy++) {
#pragma unroll
            for (int dx = 0; dx < 2; dx++) {
              float acc = 0.0f;
#pragma unroll
              for (int ky = 0; ky < 3; ky++)
#pragma unroll
                for (int kx = 0; kx < 3; kx++)
                  acc = fmaf(p[(dy + ky) * 4 + dx + kx], wv[sl][ky * 3 + kx], acc);
              float y = (acc - m_[sl]) * sc_[sl] + be_[sl];
              float sp = lif_step(v[sl][dy * 2 + dx], y);
              smax = fmaxf(smax, sp);
            }
          }
        }
        phl[tid + 256 * sl] = smax;  // == ch*72 + hy*12 + hx
        if (hown[sl])
          pool1[((size_t)(t * B + b) * 6 + hch[sl]) * (P1H * P1W) + hpy[sl] * P1W + hpx[sl]] = smax;
      }
    }
    LDS_PHASE_BARRIER();  // phl + til[nxt] writes done
    // Phase B: partial (reads phl, writes pr)
    if (oidx >= 0) {
      int i2 = oidx;
      float pt[9];
#pragma unroll
      for (int ky = 0; ky < 3; ky++)
#pragma unroll
        for (int kx = 0; kx < 3; kx++)
          pt[ky * 3 + kx] = phl[i2 * 72 + (psy + ky) * 12 + (psx + kx)];
      float p6[6];
#pragma unroll
      for (int o = 0; o < 6; o++) {
        float a = 0.0f;
#pragma unroll
        for (int k2 = 0; k2 < 9; k2++) a = fmaf(pt[k2], wsm2[(o * 6 + i2) * 9 + k2], a);
        p6[o] = a;
      }
#pragma unroll
      for (int o = 0; o < 6; o++) pr[pos40][i2][o] = p6[o];
    }
    LDS_PHASE_BARRIER();  // pr ready
    // Phase C: reduce (no barrier; next A's end-barrier separates C's pr
    // reads from next B's pr writes; A touches only til/phl).
    if (oidx >= 0) {
      double acc = 0.0;
#pragma unroll
      for (int ic = 0; ic < 6; ic++) acc += (double)pr[pos40][ic][oidx];
      s_acc += acc;
      q_acc += acc * acc;
    }
  }
  __syncthreads();
  reduce12_sel(oidx, s_acc, q_acc, partials2);
}

// ---- fuse2 + stats3: own 4x5 pooled, halo 6x7 (r20 single-buffer) ----
__global__ void fuse2_stats(const float* __restrict__ in, const float* __restrict__ w2g,
                            const float* __restrict__ w3g,
                            const float* __restrict__ mean2, const float* __restrict__ sg2,
                            const float* __restrict__ beta2,
                            float* __restrict__ pool2, double* __restrict__ partials3) {
  __shared__ float wsm2[324];
  __shared__ float wsm3[324];
  __shared__ float til[2][6][14][9];
  __shared__ float phl[6][6][7];
  __shared__ float pr[20][6][7];  // [pos][i][o]

  int tid = threadIdx.x;
  for (int k = tid; k < 324; k += 256) { wsm2[k] = w2g[k]; wsm3[k] = w3g[k]; }

  int wg = blockIdx.x;
  int b = wg / 40;
  int rem = wg % 40;
  int oy = rem / 20, ox = rem % 20;
  int iy0 = 8 * oy - 3, ix0 = 10 * ox - 3;
  constexpr int HW = H2 * W2;

  bool s_in[6];
  int s_off[6], s_lofs[6];
#pragma unroll
  for (int j = 0; j < 6; j++) {
    int k = tid + 256 * j;
    bool valid = k < 1344;
    int i = k / 224;
    int r2 = k % 224;
    int rr = r2 / 16, cc = r2 % 16;
    int hh = iy0 + rr, ww = ix0 + cc;
    s_in[j] = valid && hh >= 0 && hh < H2 && ww >= 0 && ww < W2;
    s_off[j] = i * HW + hh * W2 + ww;
    s_lofs[j] = valid ? ((cc & 1) * 756 + i * 126 + rr * 9 + (cc >> 1)) : -1;
  }
  float* tilf = &til[0][0][0][0];

  bool active = tid < 252;
  int ch = 0, hy = 0, hx = 0, py = 0, px = 0;
  bool pvalid = false, own = false;
  if (active) {
    ch = tid / 42;
    int r = tid % 42;
    hy = r / 7; hx = r % 7;
    py = 4 * oy - 1 + hy; px = 5 * ox - 1 + hx;
    pvalid = (py >= 0 && py < P2H && px >= 0 && px < P2W);
    own = (hy >= 1 && hy <= 4 && hx >= 1 && hx <= 5);
  }
  float m = active ? mean2[ch] : 0.0f;
  float sc = active ? sg2[ch] : 0.0f;
  float be = active ? beta2[ch] : 0.0f;

  int oidx = (tid < 120) ? (tid / 20) : -1;
  int pos = tid % 20;
  int psy = pos / 5, psx = pos % 5;

  float v[4] = {0.0f, 0.0f, 0.0f, 0.0f};
  double s_acc = 0.0, q_acc = 0.0;

  float rs[6] = {0.0f, 0.0f, 0.0f, 0.0f, 0.0f, 0.0f};
  {
    const float* xb = in + (size_t)(0 * B + b) * 6 * HW;
#pragma unroll
    for (int j = 0; j < 6; j++)
      if (s_in[j]) rs[j] = xb[s_off[j]];
  }

  for (int t = 0; t < T; t++) {
    __syncthreads();
#pragma unroll
    for (int j = 0; j < 6; j++)
      if (s_lofs[j] >= 0) tilf[s_lofs[j]] = rs[j];
    if (t + 1 < T) {
      const float* xb = in + (size_t)((t + 1) * B + b) * 6 * HW;
#pragma unroll
      for (int j = 0; j < 6; j++)
        if (s_in[j]) rs[j] = xb[s_off[j]];
    }
    LDS_PHASE_BARRIER();
    if (active) {
      float smax = 0.0f;
      if (pvalid) {
        int ry = 2 * hy;
        float acc4[4] = {0.0f, 0.0f, 0.0f, 0.0f};
#pragma unroll
        for (int i = 0; i < 6; i++) {
          float p[16];
#pragma unroll
          for (int r = 0; r < 4; r++) {
            p[r * 4 + 0] = til[0][i][ry + r][hx];
            p[r * 4 + 1] = til[1][i][ry + r][hx];
            p[r * 4 + 2] = til[0][i][ry + r][hx + 1];
            p[r * 4 + 3] = til[1][i][ry + r][hx + 1];
          }
          const float* wo = &wsm2[(ch * 6 + i) * 9];
#pragma unroll
          for (int dy = 0; dy < 2; dy++)
#pragma unroll
            for (int dx = 0; dx < 2; dx++) {
              float a = acc4[dy * 2 + dx];
#pragma unroll
              for (int ky = 0; ky < 3; ky++)
#pragma unroll
                for (int kx = 0; kx < 3; kx++)
                  a = fmaf(p[(dy + ky) * 4 + dx + kx], wo[ky * 3 + kx], a);
              acc4[dy * 2 + dx] = a;
            }
        }
#pragma unroll
        for (int p4 = 0; p4 < 4; p4++) {
          float y = (acc4[p4] - m) * sc + be;
          float sp = lif_step(v[p4], y);
          smax = fmaxf(smax, sp);
        }
      }
      phl[ch][hy][hx] = smax;
      if (own)
        pool2[((size_t)(t * B + b) * 6 + ch) * (P2H * P2W) + py * P2W + px] = smax;
    }
    LDS_PHASE_BARRIER();
    if (oidx >= 0) {
      float pt[9];
#pragma unroll
      for (int ky = 0; ky < 3; ky++)
#pragma unroll
        for (int kx = 0; kx < 3; kx++)
          pt[ky * 3 + kx] = phl[oidx][psy + ky][psx + kx];
      float p6[6];
#pragma unroll
      for (int o = 0; o < 6; o++) {
        float a = 0.0f;
#pragma unroll
        for (int k2 = 0; k2 < 9; k2++) a = fmaf(pt[k2], wsm3[(o * 6 + oidx) * 9 + k2], a);
        p6[o] = a;
      }
#pragma unroll
      for (int o = 0; o < 6; o++) pr[pos][oidx][o] = p6[o];
    }
    LDS_PHASE_BARRIER();
    if (oidx >= 0) {
      double acc = 0.0;
#pragma unroll
      for (int ic = 0; ic < 6; ic++) acc += (double)pr[pos][ic][oidx];
      s_acc += acc;
      q_acc += acc * acc;
    }
  }
  __syncthreads();
  reduce12_sel(oidx, s_acc, q_acc, partials3);
}

// ---- block 3 fuse: conv(6->6)+BN+LIF+pool, parity-split LDS tiles ----
template <int H, int W, int PH, int PW, int TH, int TW>
__global__ void block6_fuse_lds(const float* __restrict__ in, const float* __restrict__ wt,
                                const float* __restrict__ mean, const float* __restrict__ sg,
                                const float* __restrict__ beta, float* __restrict__ out) {
  constexpr int NTH = PH / TH, NTW = PW / TW;
  constexpr int IH = 2 * TH + 2, IW = 2 * TW + 2;
  constexpr int EW = IW / 2;
  constexpr int TILE_N = IH * IW;
  constexpr int NACT = 6 * TH * TW;
  constexpr int HW = H * W;
  __shared__ float wsm[324];
  __shared__ float til_e[6][IH][EW];
  __shared__ float til_o[6][IH][EW];

  for (int k = threadIdx.x; k < 324; k += blockDim.x) wsm[k] = wt[k];

  int wg = blockIdx.x;
  int b = wg / (NTH * NTW);
  int tid2 = wg % (NTH * NTW);
  int ty = tid2 / NTW, tx = tid2 % NTW;
  int h_in0 = 2 * (ty * TH) - 1, w_in0 = 2 * (tx * TW) - 1;

  int tid = threadIdx.x;
  int o = 0, lph = 0, lpw = 0;
  if (tid < NACT) {
    o = tid / (TH * TW);
    int r = tid % (TH * TW);
    lph = r / TW; lpw = r % TW;
  }
  float m = mean[o], s = sg[o], be = beta[o];
  float v[4] = {0.0f, 0.0f, 0.0f, 0.0f};

  for (int t = 0; t < T; t++) {
    __syncthreads();
    const float* xb = in + (size_t)(t * B + b) * 6 * HW;
    for (int k = tid; k < 6 * TILE_N; k += blockDim.x) {
      int i = k / TILE_N;
      int r2 = k % TILE_N;
      int rr = r2 / IW, cc = r2 % IW;
      int hh = h_in0 + rr, ww = w_in0 + cc;
      float val = (hh >= 0 && hh < H && ww >= 0 && ww < W) ? xb[i * HW + hh * W + ww] : 0.0f;
      if (cc & 1) til_o[i][rr][cc >> 1] = val;
      else        til_e[i][rr][cc >> 1] = val;
    }
    __syncthreads();
    if (tid < NACT) {
      int ry = 2 * lph;
      float acc[4] = {0.0f, 0.0f, 0.0f, 0.0f};
#pragma unroll
      for (int i = 0; i < 6; i++) {
        float p[16];
#pragma unroll
        for (int r = 0; r < 4; r++) {
          p[r * 4 + 0] = til_e[i][ry + r][lpw];
          p[r * 4 + 1] = til_o[i][ry + r][lpw];
          p[r * 4 + 2] = til_e[i][ry + r][lpw + 1];
          p[r * 4 + 3] = til_o[i][ry + r][lpw + 1];
        }
        const float* wo = &wsm[(o * 6 + i) * 9];
#pragma unroll
        for (int dy = 0; dy < 2; dy++)
#pragma unroll
          for (int dx = 0; dx < 2; dx++) {
            float a = acc[dy * 2 + dx];
#pragma unroll
            for (int ky = 0; ky < 3; ky++)
#pragma unroll
              for (int kx = 0; kx < 3; kx++)
                a = fmaf(p[(dy + ky) * 4 + dx + kx], wo[ky * 3 + kx], a);
            acc[dy * 2 + dx] = a;
          }
      }
      float smax = 0.0f;
#pragma unroll
      for (int p4 = 0; p4 < 4; p4++) {
        float y = (acc[p4] - m) * s + be;
        float sp = lif_step(v[p4], y);
        smax = fmaxf(smax, sp);
      }
      out[((size_t)(t * B + b) * 6 + o) * (PH * PW) + (ty * TH + lph) * PW + (tx * TW + lpw)] = smax;
    }
  }
}

// ---- FC1 matmul ----
__global__ void fc1_mm(const float* __restrict__ p3, const float* __restrict__ fw1,
                       float* __restrict__ u1) {
  int idx = blockIdx.x * blockDim.x + threadIdx.x;
  if (idx >= T * B * 100) return;
  int o = idx % 100;
  int tb = idx / 100;
  const float4* x4 = (const float4*)(p3 + (size_t)tb * 1200);
  const float4* w4 = (const float4*)(fw1 + (size_t)o * 1200);
  float acc = 0.0f;
#pragma unroll 4
  for (int k = 0; k < 300; k++) {
    float4 a = x4[k], w = w4[k];
    acc = fmaf(a.x, w.x, acc);
    acc = fmaf(a.y, w.y, acc);
    acc = fmaf(a.z, w.z, acc);
    acc = fmaf(a.w, w.w, acc);
  }
  u1[idx] = acc;
}

// ---- fc tail: fc1-LIF + fc2 + fc2-LIF, one WG per batch ----
__global__ void fc_tail(const float* __restrict__ u1, const float* __restrict__ fw2,
                        float* __restrict__ outp) {
  __shared__ float s1[100];
  __shared__ float w2s[200];
  int b = blockIdx.x;
  int tid = threadIdx.x;
  for (int k = tid; k < 200; k += 128) w2s[k] = fw2[k];
  float v1 = 0.0f, v2 = 0.0f;
  __syncthreads();
  for (int t = 0; t < T; t++) {
    if (tid < 100) {
      float sp = lif_step(v1, u1[(size_t)(t * B + b) * 100 + tid]);
      s1[tid] = sp;
    }
    __syncthreads();
    if (tid < 2) {
      const float* wr = &w2s[tid * 100];
      float acc = 0.0f;
#pragma unroll
      for (int k = 0; k < 100; k++) acc = fmaf(s1[k], wr[k], acc);
      float sp = lif_step(v2, acc);
      outp[(size_t)(t * B + b) * 2 + tid] = sp;
    }
    __syncthreads();
  }
}

extern "C" void kernel_launch(void* const* d_in, const int* in_sizes, int n_in,
                              void* d_out, int out_size, void* d_ws, size_t ws_size,
                              hipStream_t stream) {
  const float* x   = (const float*)d_in[0];
  const float* w1  = (const float*)d_in[1];
  const float* g1  = (const float*)d_in[2];
  const float* b1  = (const float*)d_in[3];
  const float* w2  = (const float*)d_in[4];
  const float* g2  = (const float*)d_in[5];
  const float* b2  = (const float*)d_in[6];
  const float* w3  = (const float*)d_in[7];
  const float* g3  = (const float*)d_in[8];
  const float* b3  = (const float*)d_in[9];
  const float* fw1 = (const float*)d_in[10];
  const float* fw2 = (const float*)d_in[11];
  float* out = (float*)d_out;

  char* ws = (char*)d_ws;
  double* part1  = (double*)(ws + OFF_PART1);
  double* partf1 = (double*)(ws + OFF_PARTF1);
  double* partf2 = (double*)(ws + OFF_PARTF2);
  float* mean1 = (float*)(ws + OFF_STATS + 0);
  float* sg1   = (float*)(ws + OFF_STATS + 32);
  float* mean2 = (float*)(ws + OFF_STATS + 64);
  float* sg2   = (float*)(ws + OFF_STATS + 96);
  float* mean3 = (float*)(ws + OFF_STATS + 128);
  float* sg3   = (float*)(ws + OFF_STATS + 160);
  float* pool1 = (float*)(ws + OFF_POOL1);
  float* pool2 = (float*)(ws + OFF_POOL2);
  float* pool3 = (float*)(ws + OFF_POOL3);
  float* u1    = (float*)(ws + OFF_U1);

  // Block 1 stats + finalize
  conv_stats_lds<1, H1, W1, 32, 100><<<NWG_S1, 256, 0, stream>>>(x, w1, part1);
  finalize_stats<<<1, 256, 0, stream>>>(part1, NWG_S1, (double)T * B * H1 * W1, g1, mean1, sg1);
  // fuse1 (+ stats for block2)
  fuse1_stats<<<NWG_F1, 256, 0, stream>>>(x, w1, w2, mean1, sg1, b1, pool1, partf1);
  finalize_stats<<<1, 256, 0, stream>>>(partf1, NWG_F1, (double)T * B * H2 * W2, g2, mean2, sg2);
  // fuse2 (+ stats for block3)
  fuse2_stats<<<NWG_F2, 256, 0, stream>>>(pool1, w2, w3, mean2, sg2, b2, pool2, partf2);
  finalize_stats<<<1, 256, 0, stream>>>(partf2, NWG_F2, (double)T * B * H3 * W3, g3, mean3, sg3);
  // Block 3 fuse
  {
    int nwg = B * (P3H / 2) * (P3W / 5);  // 640
    block6_fuse_lds<H3, W3, P3H, P3W, 2, 5><<<nwg, 64, 0, stream>>>(pool2, w3, mean3, sg3, b3, pool3);
  }
  // FC head
  {
    int n = T * B * 100;
    fc1_mm<<<(n + 255) / 256, 256, 0, stream>>>(pool3, fw1, u1);
  }
  fc_tail<<<B, 128, 0, stream>>>(u1, fw2, out);
}

// Round 26
// 432.513 us; speedup vs baseline: 1.0493x; 1.0127x over previous
//
#include <hip/hip_runtime.h>

// SNN forward: 3x (conv3x3 -> tdBN -> LIF -> maxpool2) + 2x (FC -> LIF)
// x [16,32,1,32,400] -> pool1 [16,32,6,16,200] -> pool2 [16,32,6,8,100]
//   -> pool3 [16,32,6,4,50] -> fc1 [16,32,100] -> out [16,32,2]
//
// Round-26: FINAL revert to the r20/r23 best-known 433us configuration
// (reproduced twice). r25's A/B showed fuse1-dbuf is net-negative (128->131,
// LDS 12.8->14.3KB): the barrier-halving gain < occupancy loss. Footprint
// law confirmed from 4 directions (r18/r22/r24/r25). Config: fuse1 own-4x10,
// fuse2 own-4x5, block3 2x5/64thr, fc_tail, parity-split tiles, 4-phase
// loop with LDS-only intra-iteration barriers + reg prefetch.

namespace {

constexpr int T = 16, B = 32;
constexpr int H1 = 32, W1 = 400, P1H = 16, P1W = 200;
constexpr int H2 = 16, W2 = 200, P2H = 8,  P2W = 100;
constexpr int H3 = 8,  W3 = 100, P3H = 4,  P3W = 50;

constexpr int NWG_S1 = T * B * (H1 / 32) * (W1 / 100);  // 2048
constexpr int NWG_F1 = B * (P1H / 4) * (P1W / 10);      // 2560
constexpr int NWG_F2 = B * (P2H / 4) * (P2W / 5);       // 1280

constexpr size_t OFF_PART1  = 0;
constexpr size_t OFF_PARTF1 = OFF_PART1 + (size_t)NWG_S1 * 12 * 8;
constexpr size_t OFF_PARTF2 = OFF_PARTF1 + (size_t)6400 * 12 * 8;  // slack
constexpr size_t OFF_STATS  = OFF_PARTF2 + (size_t)2560 * 12 * 8;
constexpr size_t OFF_POOL1  = 1310720;
constexpr size_t OFF_POOL2  = OFF_POOL1 + (size_t)T * B * 6 * P1H * P1W * 4;
constexpr size_t OFF_POOL3  = OFF_POOL2 + (size_t)T * B * 6 * P2H * P2W * 4;
constexpr size_t OFF_U1     = OFF_POOL3 + (size_t)T * B * 6 * P3H * P3W * 4;

} // namespace

// LDS-only phase barrier: waits own ds ops, does NOT drain vmcnt (prefetch
// loads stay in flight across it).
#define LDS_PHASE_BARRIER()                                   \
  do {                                                        \
    asm volatile("s_waitcnt lgkmcnt(0)" ::: "memory");        \
    __builtin_amdgcn_s_barrier();                             \
    __builtin_amdgcn_sched_barrier(0);                        \
  } while (0)

__device__ __forceinline__ float lif_step(float& v, float y) {
  v = v + (y - v) * 0.5f;                 // tau=2, decay_input
  float sp = (v >= 1.0f) ? 1.0f : 0.0f;   // threshold 1.0
  v = (sp > 0.0f) ? 0.0f : v;             // hard reset
  return sp;
}

// Block reduction of per-thread 6+6 double counters (array form).
__device__ __forceinline__ void reduce12(double* s, double* q, double* partials) {
  __shared__ double lds[4][12];
  int lane = threadIdx.x & 63, wid = threadIdx.x >> 6;
#pragma unroll
  for (int k = 0; k < 12; k++) {
    double v = (k < 6) ? s[k] : q[k - 6];
#pragma unroll
    for (int off = 32; off >= 1; off >>= 1) v += __shfl_down(v, off, 64);
    if (lane == 0) lds[wid][k] = v;
  }
  __syncthreads();
  if (threadIdx.x < 12) {
    partials[(size_t)blockIdx.x * 12 + threadIdx.x] =
        lds[0][threadIdx.x] + lds[1][threadIdx.x] + lds[2][threadIdx.x] + lds[3][threadIdx.x];
  }
}

// Select form: thread contributes (s_acc,q_acc) only to counter `oidx` (<0: none).
__device__ __forceinline__ void reduce12_sel(int oidx, double s_acc, double q_acc,
                                             double* partials) {
  __shared__ double lds[4][12];
  int lane = threadIdx.x & 63, wid = threadIdx.x >> 6;
#pragma unroll
  for (int k = 0; k < 12; k++) {
    double v = (k == oidx) ? s_acc : ((k == oidx + 6) ? q_acc : 0.0);
#pragma unroll
    for (int off = 32; off >= 1; off >>= 1) v += __shfl_down(v, off, 64);
    if (lane == 0) lds[wid][k] = v;
  }
  __syncthreads();
  if (threadIdx.x < 12) {
    partials[(size_t)blockIdx.x * 12 + threadIdx.x] =
        lds[0][threadIdx.x] + lds[1][threadIdx.x] + lds[2][threadIdx.x] + lds[3][threadIdx.x];
  }
}

// ---- block1 stats: conv(1->6) over x, LDS-tiled (single-shot) ----
template <int NC, int H, int W, int TH, int TW>
__global__ void conv_stats_lds(const float* __restrict__ in, const float* __restrict__ wt,
                               double* __restrict__ partials) {
  constexpr int IH = TH + 2, IW = TW + 2;
  constexpr int IWP = (IW & 1) ? IW : IW + 1;  // odd row stride
  constexpr int NW = NC * 54;
  constexpr int NTH = H / TH, NTW = W / TW;
  constexpr int NT = NTH * NTW;
  __shared__ float wsm[NW];
  __shared__ float tile[NC][IH][IWP];

  int tid = threadIdx.x;
  for (int k = tid; k < NW; k += blockDim.x) wsm[k] = wt[k];

  int wg = blockIdx.x;
  int tb = wg / NT;
  int ti = wg % NT;
  int ty = ti / NTW, tx = ti % NTW;
  int h0 = ty * TH - 1, w0 = tx * TW - 1;
  const float* xb = in + (size_t)tb * NC * H * W;

  for (int k = tid; k < NC * IH * IW; k += blockDim.x) {
    int i = k / (IH * IW);
    int r = k % (IH * IW);
    int rr = r / IW, cc = r % IW;
    int hh = h0 + rr, ww = w0 + cc;
    tile[i][rr][cc] = (hh >= 0 && hh < H && ww >= 0 && ww < W) ? xb[i * H * W + hh * W + ww] : 0.0f;
  }
  __syncthreads();

  double s[6] = {0, 0, 0, 0, 0, 0}, q[6] = {0, 0, 0, 0, 0, 0};
  for (int pos = tid; pos < TH * TW; pos += blockDim.x) {
    int ly = pos / TW, lx = pos % TW;
    float acc[6] = {0, 0, 0, 0, 0, 0};
#pragma unroll
    for (int i = 0; i < NC; i++) {
      float p[9];
#pragma unroll
      for (int ky = 0; ky < 3; ky++)
#pragma unroll
        for (int kx = 0; kx < 3; kx++) p[ky * 3 + kx] = tile[i][ly + ky][lx + kx];
#pragma unroll
      for (int o = 0; o < 6; o++) {
        float a = acc[o];
#pragma unroll
        for (int k2 = 0; k2 < 9; k2++) a = fmaf(p[k2], wsm[(o * NC + i) * 9 + k2], a);
        acc[o] = a;
      }
    }
#pragma unroll
    for (int o = 0; o < 6; o++) {
      s[o] += (double)acc[o];
      q[o] += (double)acc[o] * (double)acc[o];
    }
  }
  reduce12(s, q, partials);
}

// ---- finalize: partials -> mean[6], sg[6] ----
__global__ void finalize_stats(const double* __restrict__ partials, int nb, double n,
                               const float* __restrict__ gamma,
                               float* __restrict__ mean_out, float* __restrict__ sg_out) {
  __shared__ double lds[12][21];
  __shared__ double sums[12];
  int t = threadIdx.x;
  int k = t % 12, j = t / 12;
  if (t < 252) {
    double acc = 0.0;
    for (int b = j; b < nb; b += 21) acc += partials[(size_t)b * 12 + k];
    lds[k][j] = acc;
  }
  __syncthreads();
  if (t < 12) {
    double acc = 0.0;
#pragma unroll
    for (int j2 = 0; j2 < 21; j2++) acc += lds[t][j2];
    sums[t] = acc;
  }
  __syncthreads();
  if (t < 6) {
    double mean = sums[t] / n;
    double var = sums[t + 6] / n - mean * mean;
    double invstd = 1.0 / sqrt(var + 1e-5);
    mean_out[t] = (float)mean;
    sg_out[t] = (float)(invstd * (double)gamma[t]);
  }
}

// ---- fuse1 + stats2: own 4x10 pooled, halo 6x12 (432 positions, 2/thread) ----
// Input tile 14x26, parity-major til[2][14][13]. WG: (b, oy 0..3, ox 0..19).
__global__ void fuse1_stats(const float* __restrict__ x, const float* __restrict__ w1g,
                            const float* __restrict__ w2g,
                            const float* __restrict__ mean1, const float* __restrict__ sg1,
                            const float* __restrict__ beta1,
                            float* __restrict__ pool1, double* __restrict__ partials2) {
  __shared__ float wsm1[54];
  __shared__ float wsm2[324];
  __shared__ float til[2][14][13];
  __shared__ float phl[432];      // [ch][hy][hx] flat = ch*72 + hy*12 + hx
  __shared__ float pr[40][7][7];  // [pos][i][o], pos stride 49 (odd)

  int tid = threadIdx.x;
  for (int k = tid; k < 54; k += 256) wsm1[k] = w1g[k];
  for (int k = tid; k < 324; k += 256) wsm2[k] = w2g[k];

  int wg = blockIdx.x;
  int b = wg / 80;
  int rem = wg % 80;
  int oy = rem / 20, ox = rem % 20;
  int iy0 = 8 * oy - 3, ix0 = 20 * ox - 3;  // input tile origin (14x26)

  // staging geometry (t-invariant): 364 raw elems, 2 slots/thread
  bool s_in[2];
  int s_off[2], s_lofs[2];
#pragma unroll
  for (int j = 0; j < 2; j++) {
    int k = tid + 256 * j;
    bool valid = k < 364;
    int srr = k / 26, scc = k % 26;
    int shh = iy0 + srr, sww = ix0 + scc;
    s_in[j] = valid && shh >= 0 && shh < H1 && sww >= 0 && sww < W1;
    s_off[j] = shh * W1 + sww;
    s_lofs[j] = valid ? ((scc & 1) * 182 + srr * 13 + (scc >> 1)) : -1;
  }
  float* tilf = &til[0][0][0];

  // halo-conv geometry: 2 slots, pos = tid + 256*sl < 432
  int hch[2], hhy[2], hhx[2], hpy[2], hpx[2];
  bool hact[2], hval[2], hown[2];
  float m_[2], sc_[2], be_[2];
  float wv[2][9];
#pragma unroll
  for (int sl = 0; sl < 2; sl++) {
    int pos = tid + 256 * sl;
    hact[sl] = pos < 432;
    int p2 = hact[sl] ? pos : 0;
    int ch = p2 / 72;
    int r = p2 % 72;
    int hy = r / 12, hx = r % 12;
    hch[sl] = ch; hhy[sl] = hy; hhx[sl] = hx;
    int py = 4 * oy - 1 + hy, px = 10 * ox - 1 + hx;
    hpy[sl] = py; hpx[sl] = px;
    hval[sl] = hact[sl] && py >= 0 && py < P1H && px >= 0 && px < P1W;
    hown[sl] = hact[sl] && hy >= 1 && hy <= 4 && hx >= 1 && hx <= 10;
#pragma unroll
    for (int k = 0; k < 9; k++) wv[sl][k] = w1g[ch * 9 + k];
    m_[sl] = mean1[ch]; sc_[sl] = sg1[ch]; be_[sl] = beta1[ch];
  }

  // stats phases: 240 threads. partial: in-ch tid/40, pos40 = tid%40.
  int oidx = (tid < 240) ? (tid / 40) : -1;
  int pos40 = tid % 40;
  int psy = pos40 / 10, psx = pos40 % 10;

  float v[2][4];
#pragma unroll
  for (int sl = 0; sl < 2; sl++)
#pragma unroll
    for (int k = 0; k < 4; k++) v[sl][k] = 0.0f;
  double s_acc = 0.0, q_acc = 0.0;

  // prologue: prefetch t=0
  float rs[2] = {0.0f, 0.0f};
#pragma unroll
  for (int j = 0; j < 2; j++)
    if (s_in[j]) rs[j] = x[(size_t)(0 * B + b) * (H1 * W1) + s_off[j]];

  for (int t = 0; t < T; t++) {
    __syncthreads();  // full drain: prefetch complete, prev-iter readers done
#pragma unroll
    for (int j = 0; j < 2; j++)
      if (s_lofs[j] >= 0) tilf[s_lofs[j]] = rs[j];
    if (t + 1 < T) {
#pragma unroll
      for (int j = 0; j < 2; j++)
        if (s_in[j]) rs[j] = x[(size_t)((t + 1) * B + b) * (H1 * W1) + s_off[j]];
    }
    LDS_PHASE_BARRIER();  // tile ready; prefetch NOT drained
#pragma unroll
    for (int sl = 0; sl < 2; sl++) {
      if (hact[sl]) {
        float smax = 0.0f;
        if (hval[sl]) {
          int ry = 2 * hhy[sl], hx = hhx[sl];
          float p[16];
#pragma unroll
          for (int r = 0; r < 4; r++) {
            p[r * 4 + 0] = til[0][ry + r][hx];
            p[r * 4 + 1] = til[1][ry + r][hx];
            p[r * 4 + 2] = til[0][ry + r][hx + 1];
            p[r * 4 + 3] = til[1][ry + r][hx + 1];
          }
#pragma unroll
          for (int dy = 0; dy < 2; dy++) {
#pragma unroll
            for (int dx = 0; dx < 2; dx++) {
              float acc = 0.0f;
#pragma unroll
              for (int ky = 0; ky < 3; ky++)
#pragma unroll
                for (int kx = 0; kx < 3; kx++)
                  acc = fmaf(p[(dy + ky) * 4 + dx + kx], wv[sl][ky * 3 + kx], acc);
              float y = (acc - m_[sl]) * sc_[sl] + be_[sl];
              float sp = lif_step(v[sl][dy * 2 + dx], y);
              smax = fmaxf(smax, sp);
            }
          }
        }
        phl[tid + 256 * sl] = smax;  // == ch*72 + hy*12 + hx
        if (hown[sl])
          pool1[((size_t)(t * B + b) * 6 + hch[sl]) * (P1H * P1W) + hpy[sl] * P1W + hpx[sl]] = smax;
      }
    }
    LDS_PHASE_BARRIER();  // phl ready
    if (oidx >= 0) {  // partial: in-ch oidx(=i2), own pos (psy,psx)
      int i2 = oidx;
      float pt[9];
#pragma unroll
      for (int ky = 0; ky < 3; ky++)
#pragma unroll
        for (int kx = 0; kx < 3; kx++)
          pt[ky * 3 + kx] = phl[i2 * 72 + (psy + ky) * 12 + (psx + kx)];
      float p6[6];
#pragma unroll
      for (int o = 0; o < 6; o++) {
        float a = 0.0f;
#pragma unroll
        for (int k2 = 0; k2 < 9; k2++) a = fmaf(pt[k2], wsm2[(o * 6 + i2) * 9 + k2], a);
        p6[o] = a;
      }
#pragma unroll
      for (int o = 0; o < 6; o++) pr[pos40][i2][o] = p6[o];
    }
    LDS_PHASE_BARRIER();  // pr ready
    if (oidx >= 0) {  // reduce: out-ch oidx at pos40
      double acc = 0.0;
#pragma unroll
      for (int ic = 0; ic < 6; ic++) acc += (double)pr[pos40][ic][oidx];
      s_acc += acc;
      q_acc += acc * acc;
    }
  }
  __syncthreads();
  reduce12_sel(oidx, s_acc, q_acc, partials2);
}

// ---- fuse2 + stats3: own 4x5 pooled, halo 6x7 (252 conv threads) ----
__global__ void fuse2_stats(const float* __restrict__ in, const float* __restrict__ w2g,
                            const float* __restrict__ w3g,
                            const float* __restrict__ mean2, const float* __restrict__ sg2,
                            const float* __restrict__ beta2,
                            float* __restrict__ pool2, double* __restrict__ partials3) {
  __shared__ float wsm2[324];
  __shared__ float wsm3[324];
  __shared__ float til[2][6][14][9];
  __shared__ float phl[6][6][7];
  __shared__ float pr[20][6][7];  // [pos][i][o]

  int tid = threadIdx.x;
  for (int k = tid; k < 324; k += 256) { wsm2[k] = w2g[k]; wsm3[k] = w3g[k]; }

  int wg = blockIdx.x;
  int b = wg / 40;
  int rem = wg % 40;
  int oy = rem / 20, ox = rem % 20;
  int iy0 = 8 * oy - 3, ix0 = 10 * ox - 3;
  constexpr int HW = H2 * W2;

  bool s_in[6];
  int s_off[6], s_lofs[6];
#pragma unroll
  for (int j = 0; j < 6; j++) {
    int k = tid + 256 * j;
    bool valid = k < 1344;
    int i = k / 224;
    int r2 = k % 224;
    int rr = r2 / 16, cc = r2 % 16;
    int hh = iy0 + rr, ww = ix0 + cc;
    s_in[j] = valid && hh >= 0 && hh < H2 && ww >= 0 && ww < W2;
    s_off[j] = i * HW + hh * W2 + ww;
    s_lofs[j] = valid ? ((cc & 1) * 756 + i * 126 + rr * 9 + (cc >> 1)) : -1;
  }
  float* tilf = &til[0][0][0][0];

  bool active = tid < 252;
  int ch = 0, hy = 0, hx = 0, py = 0, px = 0;
  bool pvalid = false, own = false;
  if (active) {
    ch = tid / 42;
    int r = tid % 42;
    hy = r / 7; hx = r % 7;
    py = 4 * oy - 1 + hy; px = 5 * ox - 1 + hx;
    pvalid = (py >= 0 && py < P2H && px >= 0 && px < P2W);
    own = (hy >= 1 && hy <= 4 && hx >= 1 && hx <= 5);
  }
  float m = active ? mean2[ch] : 0.0f;
  float sc = active ? sg2[ch] : 0.0f;
  float be = active ? beta2[ch] : 0.0f;

  int oidx = (tid < 120) ? (tid / 20) : -1;
  int pos = tid % 20;
  int psy = pos / 5, psx = pos % 5;

  float v[4] = {0.0f, 0.0f, 0.0f, 0.0f};
  double s_acc = 0.0, q_acc = 0.0;

  float rs[6] = {0.0f, 0.0f, 0.0f, 0.0f, 0.0f, 0.0f};
  {
    const float* xb = in + (size_t)(0 * B + b) * 6 * HW;
#pragma unroll
    for (int j = 0; j < 6; j++)
      if (s_in[j]) rs[j] = xb[s_off[j]];
  }

  for (int t = 0; t < T; t++) {
    __syncthreads();
#pragma unroll
    for (int j = 0; j < 6; j++)
      if (s_lofs[j] >= 0) tilf[s_lofs[j]] = rs[j];
    if (t + 1 < T) {
      const float* xb = in + (size_t)((t + 1) * B + b) * 6 * HW;
#pragma unroll
      for (int j = 0; j < 6; j++)
        if (s_in[j]) rs[j] = xb[s_off[j]];
    }
    LDS_PHASE_BARRIER();
    if (active) {
      float smax = 0.0f;
      if (pvalid) {
        int ry = 2 * hy;
        float acc4[4] = {0.0f, 0.0f, 0.0f, 0.0f};
#pragma unroll
        for (int i = 0; i < 6; i++) {
          float p[16];
#pragma unroll
          for (int r = 0; r < 4; r++) {
            p[r * 4 + 0] = til[0][i][ry + r][hx];
            p[r * 4 + 1] = til[1][i][ry + r][hx];
            p[r * 4 + 2] = til[0][i][ry + r][hx + 1];
            p[r * 4 + 3] = til[1][i][ry + r][hx + 1];
          }
          const float* wo = &wsm2[(ch * 6 + i) * 9];
#pragma unroll
          for (int dy = 0; dy < 2; dy++)
#pragma unroll
            for (int dx = 0; dx < 2; dx++) {
              float a = acc4[dy * 2 + dx];
#pragma unroll
              for (int ky = 0; ky < 3; ky++)
#pragma unroll
                for (int kx = 0; kx < 3; kx++)
                  a = fmaf(p[(dy + ky) * 4 + dx + kx], wo[ky * 3 + kx], a);
              acc4[dy * 2 + dx] = a;
            }
        }
#pragma unroll
        for (int p4 = 0; p4 < 4; p4++) {
          float y = (acc4[p4] - m) * sc + be;
          float sp = lif_step(v[p4], y);
          smax = fmaxf(smax, sp);
        }
      }
      phl[ch][hy][hx] = smax;
      if (own)
        pool2[((size_t)(t * B + b) * 6 + ch) * (P2H * P2W) + py * P2W + px] = smax;
    }
    LDS_PHASE_BARRIER();
    if (oidx >= 0) {
      float pt[9];
#pragma unroll
      for (int ky = 0; ky < 3; ky++)
#pragma unroll
        for (int kx = 0; kx < 3; kx++)
          pt[ky * 3 + kx] = phl[oidx][psy + ky][psx + kx];
      float p6[6];
#pragma unroll
      for (int o = 0; o < 6; o++) {
        float a = 0.0f;
#pragma unroll
        for (int k2 = 0; k2 < 9; k2++) a = fmaf(pt[k2], wsm3[(o * 6 + oidx) * 9 + k2], a);
        p6[o] = a;
      }
#pragma unroll
      for (int o = 0; o < 6; o++) pr[pos][oidx][o] = p6[o];
    }
    LDS_PHASE_BARRIER();
    if (oidx >= 0) {
      double acc = 0.0;
#pragma unroll
      for (int ic = 0; ic < 6; ic++) acc += (double)pr[pos][ic][oidx];
      s_acc += acc;
      q_acc += acc * acc;
    }
  }
  __syncthreads();
  reduce12_sel(oidx, s_acc, q_acc, partials3);
}

// ---- block 3 fuse: conv(6->6)+BN+LIF+pool, parity-split LDS tiles ----
template <int H, int W, int PH, int PW, int TH, int TW>
__global__ void block6_fuse_lds(const float* __restrict__ in, const float* __restrict__ wt,
                                const float* __restrict__ mean, const float* __restrict__ sg,
                                const float* __restrict__ beta, float* __restrict__ out) {
  constexpr int NTH = PH / TH, NTW = PW / TW;
  constexpr int IH = 2 * TH + 2, IW = 2 * TW + 2;
  constexpr int EW = IW / 2;
  constexpr int TILE_N = IH * IW;
  constexpr int NACT = 6 * TH * TW;
  constexpr int HW = H * W;
  __shared__ float wsm[324];
  __shared__ float til_e[6][IH][EW];
  __shared__ float til_o[6][IH][EW];

  for (int k = threadIdx.x; k < 324; k += blockDim.x) wsm[k] = wt[k];

  int wg = blockIdx.x;
  int b = wg / (NTH * NTW);
  int tid2 = wg % (NTH * NTW);
  int ty = tid2 / NTW, tx = tid2 % NTW;
  int h_in0 = 2 * (ty * TH) - 1, w_in0 = 2 * (tx * TW) - 1;

  int tid = threadIdx.x;
  int o = 0, lph = 0, lpw = 0;
  if (tid < NACT) {
    o = tid / (TH * TW);
    int r = tid % (TH * TW);
    lph = r / TW; lpw = r % TW;
  }
  float m = mean[o], s = sg[o], be = beta[o];
  float v[4] = {0.0f, 0.0f, 0.0f, 0.0f};

  for (int t = 0; t < T; t++) {
    __syncthreads();
    const float* xb = in + (size_t)(t * B + b) * 6 * HW;
    for (int k = tid; k < 6 * TILE_N; k += blockDim.x) {
      int i = k / TILE_N;
      int r2 = k % TILE_N;
      int rr = r2 / IW, cc = r2 % IW;
      int hh = h_in0 + rr, ww = w_in0 + cc;
      float val = (hh >= 0 && hh < H && ww >= 0 && ww < W) ? xb[i * HW + hh * W + ww] : 0.0f;
      if (cc & 1) til_o[i][rr][cc >> 1] = val;
      else        til_e[i][rr][cc >> 1] = val;
    }
    __syncthreads();
    if (tid < NACT) {
      int ry = 2 * lph;
      float acc[4] = {0.0f, 0.0f, 0.0f, 0.0f};
#pragma unroll
      for (int i = 0; i < 6; i++) {
        float p[16];
#pragma unroll
        for (int r = 0; r < 4; r++) {
          p[r * 4 + 0] = til_e[i][ry + r][lpw];
          p[r * 4 + 1] = til_o[i][ry + r][lpw];
          p[r * 4 + 2] = til_e[i][ry + r][lpw + 1];
          p[r * 4 + 3] = til_o[i][ry + r][lpw + 1];
        }
        const float* wo = &wsm[(o * 6 + i) * 9];
#pragma unroll
        for (int dy = 0; dy < 2; dy++)
#pragma unroll
          for (int dx = 0; dx < 2; dx++) {
            float a = acc[dy * 2 + dx];
#pragma unroll
            for (int ky = 0; ky < 3; ky++)
#pragma unroll
              for (int kx = 0; kx < 3; kx++)
                a = fmaf(p[(dy + ky) * 4 + dx + kx], wo[ky * 3 + kx], a);
            acc[dy * 2 + dx] = a;
          }
      }
      float smax = 0.0f;
#pragma unroll
      for (int p4 = 0; p4 < 4; p4++) {
        float y = (acc[p4] - m) * s + be;
        float sp = lif_step(v[p4], y);
        smax = fmaxf(smax, sp);
      }
      out[((size_t)(t * B + b) * 6 + o) * (PH * PW) + (ty * TH + lph) * PW + (tx * TW + lpw)] = smax;
    }
  }
}

// ---- FC1 matmul ----
__global__ void fc1_mm(const float* __restrict__ p3, const float* __restrict__ fw1,
                       float* __restrict__ u1) {
  int idx = blockIdx.x * blockDim.x + threadIdx.x;
  if (idx >= T * B * 100) return;
  int o = idx % 100;
  int tb = idx / 100;
  const float4* x4 = (const float4*)(p3 + (size_t)tb * 1200);
  const float4* w4 = (const float4*)(fw1 + (size_t)o * 1200);
  float acc = 0.0f;
#pragma unroll 4
  for (int k = 0; k < 300; k++) {
    float4 a = x4[k], w = w4[k];
    acc = fmaf(a.x, w.x, acc);
    acc = fmaf(a.y, w.y, acc);
    acc = fmaf(a.z, w.z, acc);
    acc = fmaf(a.w, w.w, acc);
  }
  u1[idx] = acc;
}

// ---- fc tail: fc1-LIF + fc2 + fc2-LIF, one WG per batch ----
__global__ void fc_tail(const float* __restrict__ u1, const float* __restrict__ fw2,
                        float* __restrict__ outp) {
  __shared__ float s1[100];
  __shared__ float w2s[200];
  int b = blockIdx.x;
  int tid = threadIdx.x;
  for (int k = tid; k < 200; k += 128) w2s[k] = fw2[k];
  float v1 = 0.0f, v2 = 0.0f;
  __syncthreads();
  for (int t = 0; t < T; t++) {
    if (tid < 100) {
      float sp = lif_step(v1, u1[(size_t)(t * B + b) * 100 + tid]);
      s1[tid] = sp;
    }
    __syncthreads();
    if (tid < 2) {
      const float* wr = &w2s[tid * 100];
      float acc = 0.0f;
#pragma unroll
      for (int k = 0; k < 100; k++) acc = fmaf(s1[k], wr[k], acc);
      float sp = lif_step(v2, acc);
      outp[(size_t)(t * B + b) * 2 + tid] = sp;
    }
    __syncthreads();
  }
}

extern "C" void kernel_launch(void* const* d_in, const int* in_sizes, int n_in,
                              void* d_out, int out_size, void* d_ws, size_t ws_size,
                              hipStream_t stream) {
  const float* x   = (const float*)d_in[0];
  const float* w1  = (const float*)d_in[1];
  const float* g1  = (const float*)d_in[2];
  const float* b1  = (const float*)d_in[3];
  const float* w2  = (const float*)d_in[4];
  const float* g2  = (const float*)d_in[5];
  const float* b2  = (const float*)d_in[6];
  const float* w3  = (const float*)d_in[7];
  const float* g3  = (const float*)d_in[8];
  const float* b3  = (const float*)d_in[9];
  const float* fw1 = (const float*)d_in[10];
  const float* fw2 = (const float*)d_in[11];
  float* out = (float*)d_out;

  char* ws = (char*)d_ws;
  double* part1  = (double*)(ws + OFF_PART1);
  double* partf1 = (double*)(ws + OFF_PARTF1);
  double* partf2 = (double*)(ws + OFF_PARTF2);
  float* mean1 = (float*)(ws + OFF_STATS + 0);
  float* sg1   = (float*)(ws + OFF_STATS + 32);
  float* mean2 = (float*)(ws + OFF_STATS + 64);
  float* sg2   = (float*)(ws + OFF_STATS + 96);
  float* mean3 = (float*)(ws + OFF_STATS + 128);
  float* sg3   = (float*)(ws + OFF_STATS + 160);
  float* pool1 = (float*)(ws + OFF_POOL1);
  float* pool2 = (float*)(ws + OFF_POOL2);
  float* pool3 = (float*)(ws + OFF_POOL3);
  float* u1    = (float*)(ws + OFF_U1);

  // Block 1 stats + finalize
  conv_stats_lds<1, H1, W1, 32, 100><<<NWG_S1, 256, 0, stream>>>(x, w1, part1);
  finalize_stats<<<1, 256, 0, stream>>>(part1, NWG_S1, (double)T * B * H1 * W1, g1, mean1, sg1);
  // fuse1 (+ stats for block2)
  fuse1_stats<<<NWG_F1, 256, 0, stream>>>(x, w1, w2, mean1, sg1, b1, pool1, partf1);
  finalize_stats<<<1, 256, 0, stream>>>(partf1, NWG_F1, (double)T * B * H2 * W2, g2, mean2, sg2);
  // fuse2 (+ stats for block3)
  fuse2_stats<<<NWG_F2, 256, 0, stream>>>(pool1, w2, w3, mean2, sg2, b2, pool2, partf2);
  finalize_stats<<<1, 256, 0, stream>>>(partf2, NWG_F2, (double)T * B * H3 * W3, g3, mean3, sg3);
  // Block 3 fuse
  {
    int nwg = B * (P3H / 2) * (P3W / 5);  // 640
    block6_fuse_lds<H3, W3, P3H, P3W, 2, 5><<<nwg, 64, 0, stream>>>(pool2, w3, mean3, sg3, b3, pool3);
  }
  // FC head
  {
    int n = T * B * 100;
    fc1_mm<<<(n + 255) / 256, 256, 0, stream>>>(pool3, fw1, u1);
  }
  fc_tail<<<B, 128, 0, stream>>>(u1, fw2, out);
}

// Round 27
// 368.728 us; speedup vs baseline: 1.2308x; 1.1730x over previous
//
#include <hip/hip_runtime.h>

// SNN forward: 3x (conv3x3 -> tdBN -> LIF -> maxpool2) + 2x (FC -> LIF)
// x [16,32,1,32,400] -> pool1 [16,32,6,16,200] -> pool2 [16,32,6,8,100]
//   -> pool3 [16,32,6,4,50] -> fc1 [16,32,100] -> out [16,32,2]
//
// Round-27: champion r20/r23/r26 config (433us, reproduced 3x) with ONE
// isolated change: finalize_stats parallelized 1 WG -> 6 WGs (WG ch reduces
// counters ch and ch+6; 256-thread strided loads + LDS tree vs the old
// 122-long serial double-add chains). Tests whether the three 1-WG
// serialization points contribute to the ~180us unprofiled middle.

namespace {

constexpr int T = 16, B = 32;
constexpr int H1 = 32, W1 = 400, P1H = 16, P1W = 200;
constexpr int H2 = 16, W2 = 200, P2H = 8,  P2W = 100;
constexpr int H3 = 8,  W3 = 100, P3H = 4,  P3W = 50;

constexpr int NWG_S1 = T * B * (H1 / 32) * (W1 / 100);  // 2048
constexpr int NWG_F1 = B * (P1H / 4) * (P1W / 10);      // 2560
constexpr int NWG_F2 = B * (P2H / 4) * (P2W / 5);       // 1280

constexpr size_t OFF_PART1  = 0;
constexpr size_t OFF_PARTF1 = OFF_PART1 + (size_t)NWG_S1 * 12 * 8;
constexpr size_t OFF_PARTF2 = OFF_PARTF1 + (size_t)6400 * 12 * 8;  // slack
constexpr size_t OFF_STATS  = OFF_PARTF2 + (size_t)2560 * 12 * 8;
constexpr size_t OFF_POOL1  = 1310720;
constexpr size_t OFF_POOL2  = OFF_POOL1 + (size_t)T * B * 6 * P1H * P1W * 4;
constexpr size_t OFF_POOL3  = OFF_POOL2 + (size_t)T * B * 6 * P2H * P2W * 4;
constexpr size_t OFF_U1     = OFF_POOL3 + (size_t)T * B * 6 * P3H * P3W * 4;

} // namespace

// LDS-only phase barrier: waits own ds ops, does NOT drain vmcnt (prefetch
// loads stay in flight across it).
#define LDS_PHASE_BARRIER()                                   \
  do {                                                        \
    asm volatile("s_waitcnt lgkmcnt(0)" ::: "memory");        \
    __builtin_amdgcn_s_barrier();                             \
    __builtin_amdgcn_sched_barrier(0);                        \
  } while (0)

__device__ __forceinline__ float lif_step(float& v, float y) {
  v = v + (y - v) * 0.5f;                 // tau=2, decay_input
  float sp = (v >= 1.0f) ? 1.0f : 0.0f;   // threshold 1.0
  v = (sp > 0.0f) ? 0.0f : v;             // hard reset
  return sp;
}

// Block reduction of per-thread 6+6 double counters (array form).
__device__ __forceinline__ void reduce12(double* s, double* q, double* partials) {
  __shared__ double lds[4][12];
  int lane = threadIdx.x & 63, wid = threadIdx.x >> 6;
#pragma unroll
  for (int k = 0; k < 12; k++) {
    double v = (k < 6) ? s[k] : q[k - 6];
#pragma unroll
    for (int off = 32; off >= 1; off >>= 1) v += __shfl_down(v, off, 64);
    if (lane == 0) lds[wid][k] = v;
  }
  __syncthreads();
  if (threadIdx.x < 12) {
    partials[(size_t)blockIdx.x * 12 + threadIdx.x] =
        lds[0][threadIdx.x] + lds[1][threadIdx.x] + lds[2][threadIdx.x] + lds[3][threadIdx.x];
  }
}

// Select form: thread contributes (s_acc,q_acc) only to counter `oidx` (<0: none).
__device__ __forceinline__ void reduce12_sel(int oidx, double s_acc, double q_acc,
                                             double* partials) {
  __shared__ double lds[4][12];
  int lane = threadIdx.x & 63, wid = threadIdx.x >> 6;
#pragma unroll
  for (int k = 0; k < 12; k++) {
    double v = (k == oidx) ? s_acc : ((k == oidx + 6) ? q_acc : 0.0);
#pragma unroll
    for (int off = 32; off >= 1; off >>= 1) v += __shfl_down(v, off, 64);
    if (lane == 0) lds[wid][k] = v;
  }
  __syncthreads();
  if (threadIdx.x < 12) {
    partials[(size_t)blockIdx.x * 12 + threadIdx.x] =
        lds[0][threadIdx.x] + lds[1][threadIdx.x] + lds[2][threadIdx.x] + lds[3][threadIdx.x];
  }
}

// ---- block1 stats: conv(1->6) over x, LDS-tiled (single-shot) ----
template <int NC, int H, int W, int TH, int TW>
__global__ void conv_stats_lds(const float* __restrict__ in, const float* __restrict__ wt,
                               double* __restrict__ partials) {
  constexpr int IH = TH + 2, IW = TW + 2;
  constexpr int IWP = (IW & 1) ? IW : IW + 1;  // odd row stride
  constexpr int NW = NC * 54;
  constexpr int NTH = H / TH, NTW = W / TW;
  constexpr int NT = NTH * NTW;
  __shared__ float wsm[NW];
  __shared__ float tile[NC][IH][IWP];

  int tid = threadIdx.x;
  for (int k = tid; k < NW; k += blockDim.x) wsm[k] = wt[k];

  int wg = blockIdx.x;
  int tb = wg / NT;
  int ti = wg % NT;
  int ty = ti / NTW, tx = ti % NTW;
  int h0 = ty * TH - 1, w0 = tx * TW - 1;
  const float* xb = in + (size_t)tb * NC * H * W;

  for (int k = tid; k < NC * IH * IW; k += blockDim.x) {
    int i = k / (IH * IW);
    int r = k % (IH * IW);
    int rr = r / IW, cc = r % IW;
    int hh = h0 + rr, ww = w0 + cc;
    tile[i][rr][cc] = (hh >= 0 && hh < H && ww >= 0 && ww < W) ? xb[i * H * W + hh * W + ww] : 0.0f;
  }
  __syncthreads();

  double s[6] = {0, 0, 0, 0, 0, 0}, q[6] = {0, 0, 0, 0, 0, 0};
  for (int pos = tid; pos < TH * TW; pos += blockDim.x) {
    int ly = pos / TW, lx = pos % TW;
    float acc[6] = {0, 0, 0, 0, 0, 0};
#pragma unroll
    for (int i = 0; i < NC; i++) {
      float p[9];
#pragma unroll
      for (int ky = 0; ky < 3; ky++)
#pragma unroll
        for (int kx = 0; kx < 3; kx++) p[ky * 3 + kx] = tile[i][ly + ky][lx + kx];
#pragma unroll
      for (int o = 0; o < 6; o++) {
        float a = acc[o];
#pragma unroll
        for (int k2 = 0; k2 < 9; k2++) a = fmaf(p[k2], wsm[(o * NC + i) * 9 + k2], a);
        acc[o] = a;
      }
    }
#pragma unroll
    for (int o = 0; o < 6; o++) {
      s[o] += (double)acc[o];
      q[o] += (double)acc[o] * (double)acc[o];
    }
  }
  reduce12(s, q, partials);
}

// ---- finalize: partials -> mean[6], sg[6]; 6 WGs, WG ch handles ch & ch+6 ----
__global__ void finalize_stats(const double* __restrict__ partials, int nb, double n,
                               const float* __restrict__ gamma,
                               float* __restrict__ mean_out, float* __restrict__ sg_out) {
  __shared__ double red0[256];
  __shared__ double red1[256];
  int ch = blockIdx.x;
  int tid = threadIdx.x;
  double a0 = 0.0, a1 = 0.0;
  for (int b = tid; b < nb; b += 256) {
    a0 += partials[(size_t)b * 12 + ch];
    a1 += partials[(size_t)b * 12 + ch + 6];
  }
  red0[tid] = a0;
  red1[tid] = a1;
  __syncthreads();
#pragma unroll
  for (int off = 128; off >= 1; off >>= 1) {
    if (tid < off) {
      red0[tid] += red0[tid + off];
      red1[tid] += red1[tid + off];
    }
    __syncthreads();
  }
  if (tid == 0) {
    double mean = red0[0] / n;
    double var = red1[0] / n - mean * mean;
    double invstd = 1.0 / sqrt(var + 1e-5);
    mean_out[ch] = (float)mean;
    sg_out[ch] = (float)(invstd * (double)gamma[ch]);
  }
}

// ---- fuse1 + stats2: own 4x10 pooled, halo 6x12 (432 positions, 2/thread) ----
// Input tile 14x26, parity-major til[2][14][13]. WG: (b, oy 0..3, ox 0..19).
__global__ void fuse1_stats(const float* __restrict__ x, const float* __restrict__ w1g,
                            const float* __restrict__ w2g,
                            const float* __restrict__ mean1, const float* __restrict__ sg1,
                            const float* __restrict__ beta1,
                            float* __restrict__ pool1, double* __restrict__ partials2) {
  __shared__ float wsm1[54];
  __shared__ float wsm2[324];
  __shared__ float til[2][14][13];
  __shared__ float phl[432];      // [ch][hy][hx] flat = ch*72 + hy*12 + hx
  __shared__ float pr[40][7][7];  // [pos][i][o], pos stride 49 (odd)

  int tid = threadIdx.x;
  for (int k = tid; k < 54; k += 256) wsm1[k] = w1g[k];
  for (int k = tid; k < 324; k += 256) wsm2[k] = w2g[k];

  int wg = blockIdx.x;
  int b = wg / 80;
  int rem = wg % 80;
  int oy = rem / 20, ox = rem % 20;
  int iy0 = 8 * oy - 3, ix0 = 20 * ox - 3;  // input tile origin (14x26)

  // staging geometry (t-invariant): 364 raw elems, 2 slots/thread
  bool s_in[2];
  int s_off[2], s_lofs[2];
#pragma unroll
  for (int j = 0; j < 2; j++) {
    int k = tid + 256 * j;
    bool valid = k < 364;
    int srr = k / 26, scc = k % 26;
    int shh = iy0 + srr, sww = ix0 + scc;
    s_in[j] = valid && shh >= 0 && shh < H1 && sww >= 0 && sww < W1;
    s_off[j] = shh * W1 + sww;
    s_lofs[j] = valid ? ((scc & 1) * 182 + srr * 13 + (scc >> 1)) : -1;
  }
  float* tilf = &til[0][0][0];

  // halo-conv geometry: 2 slots, pos = tid + 256*sl < 432
  int hch[2], hhy[2], hhx[2], hpy[2], hpx[2];
  bool hact[2], hval[2], hown[2];
  float m_[2], sc_[2], be_[2];
  float wv[2][9];
#pragma unroll
  for (int sl = 0; sl < 2; sl++) {
    int pos = tid + 256 * sl;
    hact[sl] = pos < 432;
    int p2 = hact[sl] ? pos : 0;
    int ch = p2 / 72;
    int r = p2 % 72;
    int hy = r / 12, hx = r % 12;
    hch[sl] = ch; hhy[sl] = hy; hhx[sl] = hx;
    int py = 4 * oy - 1 + hy, px = 10 * ox - 1 + hx;
    hpy[sl] = py; hpx[sl] = px;
    hval[sl] = hact[sl] && py >= 0 && py < P1H && px >= 0 && px < P1W;
    hown[sl] = hact[sl] && hy >= 1 && hy <= 4 && hx >= 1 && hx <= 10;
#pragma unroll
    for (int k = 0; k < 9; k++) wv[sl][k] = w1g[ch * 9 + k];
    m_[sl] = mean1[ch]; sc_[sl] = sg1[ch]; be_[sl] = beta1[ch];
  }

  // stats phases: 240 threads. partial: in-ch tid/40, pos40 = tid%40.
  int oidx = (tid < 240) ? (tid / 40) : -1;
  int pos40 = tid % 40;
  int psy = pos40 / 10, psx = pos40 % 10;

  float v[2][4];
#pragma unroll
  for (int sl = 0; sl < 2; sl++)
#pragma unroll
    for (int k = 0; k < 4; k++) v[sl][k] = 0.0f;
  double s_acc = 0.0, q_acc = 0.0;

  // prologue: prefetch t=0
  float rs[2] = {0.0f, 0.0f};
#pragma unroll
  for (int j = 0; j < 2; j++)
    if (s_in[j]) rs[j] = x[(size_t)(0 * B + b) * (H1 * W1) + s_off[j]];

  for (int t = 0; t < T; t++) {
    __syncthreads();  // full drain: prefetch complete, prev-iter readers done
#pragma unroll
    for (int j = 0; j < 2; j++)
      if (s_lofs[j] >= 0) tilf[s_lofs[j]] = rs[j];
    if (t + 1 < T) {
#pragma unroll
      for (int j = 0; j < 2; j++)
        if (s_in[j]) rs[j] = x[(size_t)((t + 1) * B + b) * (H1 * W1) + s_off[j]];
    }
    LDS_PHASE_BARRIER();  // tile ready; prefetch NOT drained
#pragma unroll
    for (int sl = 0; sl < 2; sl++) {
      if (hact[sl]) {
        float smax = 0.0f;
        if (hval[sl]) {
          int ry = 2 * hhy[sl], hx = hhx[sl];
          float p[16];
#pragma unroll
          for (int r = 0; r < 4; r++) {
            p[r * 4 + 0] = til[0][ry + r][hx];
            p[r * 4 + 1] = til[1][ry + r][hx];
            p[r * 4 + 2] = til[0][ry + r][hx + 1];
            p[r * 4 + 3] = til[1][ry + r][hx + 1];
          }
#pragma unroll
          for (int dy = 0; dy < 2; dy++) {
#pragma unroll
            for (int dx = 0; dx < 2; dx++) {
              float acc = 0.0f;
#pragma unroll
              for (int ky = 0; ky < 3; ky++)
#pragma unroll
                for (int kx = 0; kx < 3; kx++)
                  acc = fmaf(p[(dy + ky) * 4 + dx + kx], wv[sl][ky * 3 + kx], acc);
              float y = (acc - m_[sl]) * sc_[sl] + be_[sl];
              float sp = lif_step(v[sl][dy * 2 + dx], y);
              smax = fmaxf(smax, sp);
            }
          }
        }
        phl[tid + 256 * sl] = smax;  // == ch*72 + hy*12 + hx
        if (hown[sl])
          pool1[((size_t)(t * B + b) * 6 + hch[sl]) * (P1H * P1W) + hpy[sl] * P1W + hpx[sl]] = smax;
      }
    }
    LDS_PHASE_BARRIER();  // phl ready
    if (oidx >= 0) {  // partial: in-ch oidx(=i2), own pos (psy,psx)
      int i2 = oidx;
      float pt[9];
#pragma unroll
      for (int ky = 0; ky < 3; ky++)
#pragma unroll
        for (int kx = 0; kx < 3; kx++)
          pt[ky * 3 + kx] = phl[i2 * 72 + (psy + ky) * 12 + (psx + kx)];
      float p6[6];
#pragma unroll
      for (int o = 0; o < 6; o++) {
        float a = 0.0f;
#pragma unroll
        for (int k2 = 0; k2 < 9; k2++) a = fmaf(pt[k2], wsm2[(o * 6 + i2) * 9 + k2], a);
        p6[o] = a;
      }
#pragma unroll
      for (int o = 0; o < 6; o++) pr[pos40][i2][o] = p6[o];
    }
    LDS_PHASE_BARRIER();  // pr ready
    if (oidx >= 0) {  // reduce: out-ch oidx at pos40
      double acc = 0.0;
#pragma unroll
      for (int ic = 0; ic < 6; ic++) acc += (double)pr[pos40][ic][oidx];
      s_acc += acc;
      q_acc += acc * acc;
    }
  }
  __syncthreads();
  reduce12_sel(oidx, s_acc, q_acc, partials2);
}

// ---- fuse2 + stats3: own 4x5 pooled, halo 6x7 (252 conv threads) ----
__global__ void fuse2_stats(const float* __restrict__ in, const float* __restrict__ w2g,
                            const float* __restrict__ w3g,
                            const float* __restrict__ mean2, const float* __restrict__ sg2,
                            const float* __restrict__ beta2,
                            float* __restrict__ pool2, double* __restrict__ partials3) {
  __shared__ float wsm2[324];
  __shared__ float wsm3[324];
  __shared__ float til[2][6][14][9];
  __shared__ float phl[6][6][7];
  __shared__ float pr[20][6][7];  // [pos][i][o]

  int tid = threadIdx.x;
  for (int k = tid; k < 324; k += 256) { wsm2[k] = w2g[k]; wsm3[k] = w3g[k]; }

  int wg = blockIdx.x;
  int b = wg / 40;
  int rem = wg % 40;
  int oy = rem / 20, ox = rem % 20;
  int iy0 = 8 * oy - 3, ix0 = 10 * ox - 3;
  constexpr int HW = H2 * W2;

  bool s_in[6];
  int s_off[6], s_lofs[6];
#pragma unroll
  for (int j = 0; j < 6; j++) {
    int k = tid + 256 * j;
    bool valid = k < 1344;
    int i = k / 224;
    int r2 = k % 224;
    int rr = r2 / 16, cc = r2 % 16;
    int hh = iy0 + rr, ww = ix0 + cc;
    s_in[j] = valid && hh >= 0 && hh < H2 && ww >= 0 && ww < W2;
    s_off[j] = i * HW + hh * W2 + ww;
    s_lofs[j] = valid ? ((cc & 1) * 756 + i * 126 + rr * 9 + (cc >> 1)) : -1;
  }
  float* tilf = &til[0][0][0][0];

  bool active = tid < 252;
  int ch = 0, hy = 0, hx = 0, py = 0, px = 0;
  bool pvalid = false, own = false;
  if (active) {
    ch = tid / 42;
    int r = tid % 42;
    hy = r / 7; hx = r % 7;
    py = 4 * oy - 1 + hy; px = 5 * ox - 1 + hx;
    pvalid = (py >= 0 && py < P2H && px >= 0 && px < P2W);
    own = (hy >= 1 && hy <= 4 && hx >= 1 && hx <= 5);
  }
  float m = active ? mean2[ch] : 0.0f;
  float sc = active ? sg2[ch] : 0.0f;
  float be = active ? beta2[ch] : 0.0f;

  int oidx = (tid < 120) ? (tid / 20) : -1;
  int pos = tid % 20;
  int psy = pos / 5, psx = pos % 5;

  float v[4] = {0.0f, 0.0f, 0.0f, 0.0f};
  double s_acc = 0.0, q_acc = 0.0;

  float rs[6] = {0.0f, 0.0f, 0.0f, 0.0f, 0.0f, 0.0f};
  {
    const float* xb = in + (size_t)(0 * B + b) * 6 * HW;
#pragma unroll
    for (int j = 0; j < 6; j++)
      if (s_in[j]) rs[j] = xb[s_off[j]];
  }

  for (int t = 0; t < T; t++) {
    __syncthreads();
#pragma unroll
    for (int j = 0; j < 6; j++)
      if (s_lofs[j] >= 0) tilf[s_lofs[j]] = rs[j];
    if (t + 1 < T) {
      const float* xb = in + (size_t)((t + 1) * B + b) * 6 * HW;
#pragma unroll
      for (int j = 0; j < 6; j++)
        if (s_in[j]) rs[j] = xb[s_off[j]];
    }
    LDS_PHASE_BARRIER();
    if (active) {
      float smax = 0.0f;
      if (pvalid) {
        int ry = 2 * hy;
        float acc4[4] = {0.0f, 0.0f, 0.0f, 0.0f};
#pragma unroll
        for (int i = 0; i < 6; i++) {
          float p[16];
#pragma unroll
          for (int r = 0; r < 4; r++) {
            p[r * 4 + 0] = til[0][i][ry + r][hx];
            p[r * 4 + 1] = til[1][i][ry + r][hx];
            p[r * 4 + 2] = til[0][i][ry + r][hx + 1];
            p[r * 4 + 3] = til[1][i][ry + r][hx + 1];
          }
          const float* wo = &wsm2[(ch * 6 + i) * 9];
#pragma unroll
          for (int dy = 0; dy < 2; dy++)
#pragma unroll
            for (int dx = 0; dx < 2; dx++) {
              float a = acc4[dy * 2 + dx];
#pragma unroll
              for (int ky = 0; ky < 3; ky++)
#pragma unroll
                for (int kx = 0; kx < 3; kx++)
                  a = fmaf(p[(dy + ky) * 4 + dx + kx], wo[ky * 3 + kx], a);
              acc4[dy * 2 + dx] = a;
            }
        }
#pragma unroll
        for (int p4 = 0; p4 < 4; p4++) {
          float y = (acc4[p4] - m) * sc + be;
          float sp = lif_step(v[p4], y);
          smax = fmaxf(smax, sp);
        }
      }
      phl[ch][hy][hx] = smax;
      if (own)
        pool2[((size_t)(t * B + b) * 6 + ch) * (P2H * P2W) + py * P2W + px] = smax;
    }
    LDS_PHASE_BARRIER();
    if (oidx >= 0) {
      float pt[9];
#pragma unroll
      for (int ky = 0; ky < 3; ky++)
#pragma unroll
        for (int kx = 0; kx < 3; kx++)
          pt[ky * 3 + kx] = phl[oidx][psy + ky][psx + kx];
      float p6[6];
#pragma unroll
      for (int o = 0; o < 6; o++) {
        float a = 0.0f;
#pragma unroll
        for (int k2 = 0; k2 < 9; k2++) a = fmaf(pt[k2], wsm3[(o * 6 + oidx) * 9 + k2], a);
        p6[o] = a;
      }
#pragma unroll
      for (int o = 0; o < 6; o++) pr[pos][oidx][o] = p6[o];
    }
    LDS_PHASE_BARRIER();
    if (oidx >= 0) {
      double acc = 0.0;
#pragma unroll
      for (int ic = 0; ic < 6; ic++) acc += (double)pr[pos][ic][oidx];
      s_acc += acc;
      q_acc += acc * acc;
    }
  }
  __syncthreads();
  reduce12_sel(oidx, s_acc, q_acc, partials3);
}

// ---- block 3 fuse: conv(6->6)+BN+LIF+pool, parity-split LDS tiles ----
template <int H, int W, int PH, int PW, int TH, int TW>
__global__ void block6_fuse_lds(const float* __restrict__ in, const float* __restrict__ wt,
                                const float* __restrict__ mean, const float* __restrict__ sg,
                                const float* __restrict__ beta, float* __restrict__ out) {
  constexpr int NTH = PH / TH, NTW = PW / TW;
  constexpr int IH = 2 * TH + 2, IW = 2 * TW + 2;
  constexpr int EW = IW / 2;
  constexpr int TILE_N = IH * IW;
  constexpr int NACT = 6 * TH * TW;
  constexpr int HW = H * W;
  __shared__ float wsm[324];
  __shared__ float til_e[6][IH][EW];
  __shared__ float til_o[6][IH][EW];

  for (int k = threadIdx.x; k < 324; k += blockDim.x) wsm[k] = wt[k];

  int wg = blockIdx.x;
  int b = wg / (NTH * NTW);
  int tid2 = wg % (NTH * NTW);
  int ty = tid2 / NTW, tx = tid2 % NTW;
  int h_in0 = 2 * (ty * TH) - 1, w_in0 = 2 * (tx * TW) - 1;

  int tid = threadIdx.x;
  int o = 0, lph = 0, lpw = 0;
  if (tid < NACT) {
    o = tid / (TH * TW);
    int r = tid % (TH * TW);
    lph = r / TW; lpw = r % TW;
  }
  float m = mean[o], s = sg[o], be = beta[o];
  float v[4] = {0.0f, 0.0f, 0.0f, 0.0f};

  for (int t = 0; t < T; t++) {
    __syncthreads();
    const float* xb = in + (size_t)(t * B + b) * 6 * HW;
    for (int k = tid; k < 6 * TILE_N; k += blockDim.x) {
      int i = k / TILE_N;
      int r2 = k % TILE_N;
      int rr = r2 / IW, cc = r2 % IW;
      int hh = h_in0 + rr, ww = w_in0 + cc;
      float val = (hh >= 0 && hh < H && ww >= 0 && ww < W) ? xb[i * HW + hh * W + ww] : 0.0f;
      if (cc & 1) til_o[i][rr][cc >> 1] = val;
      else        til_e[i][rr][cc >> 1] = val;
    }
    __syncthreads();
    if (tid < NACT) {
      int ry = 2 * lph;
      float acc[4] = {0.0f, 0.0f, 0.0f, 0.0f};
#pragma unroll
      for (int i = 0; i < 6; i++) {
        float p[16];
#pragma unroll
        for (int r = 0; r < 4; r++) {
          p[r * 4 + 0] = til_e[i][ry + r][lpw];
          p[r * 4 + 1] = til_o[i][ry + r][lpw];
          p[r * 4 + 2] = til_e[i][ry + r][lpw + 1];
          p[r * 4 + 3] = til_o[i][ry + r][lpw + 1];
        }
        const float* wo = &wsm[(o * 6 + i) * 9];
#pragma unroll
        for (int dy = 0; dy < 2; dy++)
#pragma unroll
          for (int dx = 0; dx < 2; dx++) {
            float a = acc[dy * 2 + dx];
#pragma unroll
            for (int ky = 0; ky < 3; ky++)
#pragma unroll
              for (int kx = 0; kx < 3; kx++)
                a = fmaf(p[(dy + ky) * 4 + dx + kx], wo[ky * 3 + kx], a);
            acc[dy * 2 + dx] = a;
          }
      }
      float smax = 0.0f;
#pragma unroll
      for (int p4 = 0; p4 < 4; p4++) {
        float y = (acc[p4] - m) * s + be;
        float sp = lif_step(v[p4], y);
        smax = fmaxf(smax, sp);
      }
      out[((size_t)(t * B + b) * 6 + o) * (PH * PW) + (ty * TH + lph) * PW + (tx * TW + lpw)] = smax;
    }
  }
}

// ---- FC1 matmul ----
__global__ void fc1_mm(const float* __restrict__ p3, const float* __restrict__ fw1,
                       float* __restrict__ u1) {
  int idx = blockIdx.x * blockDim.x + threadIdx.x;
  if (idx >= T * B * 100) return;
  int o = idx % 100;
  int tb = idx / 100;
  const float4* x4 = (const float4*)(p3 + (size_t)tb * 1200);
  const float4* w4 = (const float4*)(fw1 + (size_t)o * 1200);
  float acc = 0.0f;
#pragma unroll 4
  for (int k = 0; k < 300; k++) {
    float4 a = x4[k], w = w4[k];
    acc = fmaf(a.x, w.x, acc);
    acc = fmaf(a.y, w.y, acc);
    acc = fmaf(a.z, w.z, acc);
    acc = fmaf(a.w, w.w, acc);
  }
  u1[idx] = acc;
}

// ---- fc tail: fc1-LIF + fc2 + fc2-LIF, one WG per batch ----
__global__ void fc_tail(const float* __restrict__ u1, const float* __restrict__ fw2,
                        float* __restrict__ outp) {
  __shared__ float s1[100];
  __shared__ float w2s[200];
  int b = blockIdx.x;
  int tid = threadIdx.x;
  for (int k = tid; k < 200; k += 128) w2s[k] = fw2[k];
  float v1 = 0.0f, v2 = 0.0f;
  __syncthreads();
  for (int t = 0; t < T; t++) {
    if (tid < 100) {
      float sp = lif_step(v1, u1[(size_t)(t * B + b) * 100 + tid]);
      s1[tid] = sp;
    }
    __syncthreads();
    if (tid < 2) {
      const float* wr = &w2s[tid * 100];
      float acc = 0.0f;
#pragma unroll
      for (int k = 0; k < 100; k++) acc = fmaf(s1[k], wr[k], acc);
      float sp = lif_step(v2, acc);
      outp[(size_t)(t * B + b) * 2 + tid] = sp;
    }
    __syncthreads();
  }
}

extern "C" void kernel_launch(void* const* d_in, const int* in_sizes, int n_in,
                              void* d_out, int out_size, void* d_ws, size_t ws_size,
                              hipStream_t stream) {
  const float* x   = (const float*)d_in[0];
  const float* w1  = (const float*)d_in[1];
  const float* g1  = (const float*)d_in[2];
  const float* b1  = (const float*)d_in[3];
  const float* w2  = (const float*)d_in[4];
  const float* g2  = (const float*)d_in[5];
  const float* b2  = (const float*)d_in[6];
  const float* w3  = (const float*)d_in[7];
  const float* g3  = (const float*)d_in[8];
  const float* b3  = (const float*)d_in[9];
  const float* fw1 = (const float*)d_in[10];
  const float* fw2 = (const float*)d_in[11];
  float* out = (float*)d_out;

  char* ws = (char*)d_ws;
  double* part1  = (double*)(ws + OFF_PART1);
  double* partf1 = (double*)(ws + OFF_PARTF1);
  double* partf2 = (double*)(ws + OFF_PARTF2);
  float* mean1 = (float*)(ws + OFF_STATS + 0);
  float* sg1   = (float*)(ws + OFF_STATS + 32);
  float* mean2 = (float*)(ws + OFF_STATS + 64);
  float* sg2   = (float*)(ws + OFF_STATS + 96);
  float* mean3 = (float*)(ws + OFF_STATS + 128);
  float* sg3   = (float*)(ws + OFF_STATS + 160);
  float* pool1 = (float*)(ws + OFF_POOL1);
  float* pool2 = (float*)(ws + OFF_POOL2);
  float* pool3 = (float*)(ws + OFF_POOL3);
  float* u1    = (float*)(ws + OFF_U1);

  // Block 1 stats + finalize
  conv_stats_lds<1, H1, W1, 32, 100><<<NWG_S1, 256, 0, stream>>>(x, w1, part1);
  finalize_stats<<<6, 256, 0, stream>>>(part1, NWG_S1, (double)T * B * H1 * W1, g1, mean1, sg1);
  // fuse1 (+ stats for block2)
  fuse1_stats<<<NWG_F1, 256, 0, stream>>>(x, w1, w2, mean1, sg1, b1, pool1, partf1);
  finalize_stats<<<6, 256, 0, stream>>>(partf1, NWG_F1, (double)T * B * H2 * W2, g2, mean2, sg2);
  // fuse2 (+ stats for block3)
  fuse2_stats<<<NWG_F2, 256, 0, stream>>>(pool1, w2, w3, mean2, sg2, b2, pool2, partf2);
  finalize_stats<<<6, 256, 0, stream>>>(partf2, NWG_F2, (double)T * B * H3 * W3, g3, mean3, sg3);
  // Block 3 fuse
  {
    int nwg = B * (P3H / 2) * (P3W / 5);  // 640
    block6_fuse_lds<H3, W3, P3H, P3W, 2, 5><<<nwg, 64, 0, stream>>>(pool2, w3, mean3, sg3, b3, pool3);
  }
  // FC head
  {
    int n = T * B * 100;
    fc1_mm<<<(n + 255) / 256, 256, 0, stream>>>(pool3, fw1, u1);
  }
  fc_tail<<<B, 128, 0, stream>>>(u1, fw2, out);
}